// Round 3
// baseline (5824.786 us; speedup 1.0000x reference)
//
#include <hip/hip_runtime.h>

// LocalAttention P=7 window attention — split-pipeline bf16 MFMA.
// x:[32,192,56,56] f32 -> out:[32,192,56,56] f32 ++ attn:[2048,8,49,49] f32
// K1 xt_prep: x -> xt[win][64][192] bf16 (+ weight cvt + bias table)
// K2 qkvv  : GEMMs -> Q,K [win][49][256] bf16 ; Vt [win][256][64] bf16
// K3 la_attn: per window: S=K.Q^T, softmax, attn out, O=Vt.P^T, Wo proj, out

#define NWIN 2048
#define OUT0 19267584L

typedef __attribute__((ext_vector_type(8))) short bf16x8;
typedef __attribute__((ext_vector_type(4))) float f32x4;
typedef __attribute__((ext_vector_type(4), aligned(4))) float f32x4u;  // 4B-aligned vec store

#define MFMA(a, b, c) __builtin_amdgcn_mfma_f32_16x16x32_bf16(a, b, c, 0, 0, 0)

__device__ __forceinline__ unsigned short f2b(float f) {
  unsigned u = __builtin_bit_cast(unsigned, f);
  return (unsigned short)((u + 0x7FFFu + ((u >> 16) & 1u)) >> 16);
}
__device__ __forceinline__ unsigned pk2(float a, float b) {
  return (unsigned)f2b(a) | ((unsigned)f2b(b) << 16);
}

// ---- workspace layout ----
// xt  : 2048*64*192*2                 = 50,331,648
// Q,K : (2048*49+64)*256*2 each       = 51,412,992
// Vt  : 2048*256*64*2                 = 67,108,864
// wqkv 294,912 ; wo 98,304 ; bias 9,604            total ~220.7 MB
#define XT_ELEMS   (2048L * 64 * 192)
#define QK_ROWS    (2048L * 49 + 64)
#define Q_OFF      (XT_ELEMS * 2)
#define K_OFF      (Q_OFF + QK_ROWS * 256 * 2)
#define V_OFF      (K_OFF + QK_ROWS * 256 * 2)
#define WQKV_OFF   (V_OFF + 2048L * 256 * 64 * 2)
#define WO_OFF     (WQKV_OFF + 768L * 192 * 2)
#define BIAS_OFF   (WO_OFF + 192L * 256 * 2)

// ================= K1: window transpose + prep =================
__global__ __launch_bounds__(256) void xt_prep(
    const float* __restrict__ x, const float* __restrict__ mask,
    const float* __restrict__ Wq, const float* __restrict__ Wkv,
    const float* __restrict__ Wo, const float* __restrict__ pos,
    unsigned short* __restrict__ xt, unsigned short* __restrict__ wqkv,
    unsigned short* __restrict__ wo, float* __restrict__ bias)
{
  __shared__ float sXw[192][53];
  const int tid = threadIdx.x;
  const int widx = blockIdx.x;
  const int bi = widx >> 6, w1 = (widx >> 3) & 7, w2 = widx & 7;
  const long xbase = (long)bi * 192 * 3136 + (w1 * 7) * 56 + w2 * 7;

  for (int idx = tid; idx < 192 * 49; idx += 256) {
    int c = idx / 49, t = idx - c * 49;
    sXw[c][t] = x[xbase + c * 3136 + (t / 7) * 56 + (t % 7)];
  }
  // fold in one-shot prep work (striped across the grid)
  {
    int gid = widx * 256 + tid;
    if (gid < 147456)       wqkv[gid] = f2b(gid < 49152 ? Wq[gid] : Wkv[gid - 49152]);
    else if (gid < 196608)  { int i = gid - 147456; wo[i] = f2b(Wo[i]); }
    else if (gid < 199009)  {
      int i = gid - 196608;
      int tq = i / 49, tk = i - tq * 49;
      int r0 = tk / 7 - tq / 7 + 6, r1 = tk % 7 - tq % 7 + 6;
      bias[i] = mask[i] + pos[r0 * 13 + r1];
    }
  }
  __syncthreads();
  unsigned short* xw = xt + (long)widx * 64 * 192;
  for (int idx = tid; idx < 64 * 192; idx += 256) {
    int t = idx / 192, c = idx - t * 192;
    xw[idx] = (t < 49) ? f2b(sXw[c][t]) : (unsigned short)0;
  }
}

// ================= K2: QKV GEMMs (no LDS, direct frags) =================
// blocks 0..4095   : Q/K  D[e][t], e in [0,512)  (4 m-tiles x 1024 n-tiles)
// blocks 4096..6143: V    D[t][e], e in [0,256)  (1024 m-tiles x 2 n-tiles)
__global__ __launch_bounds__(256, 3) void qkvv_gemm(
    const unsigned short* __restrict__ xt, const unsigned short* __restrict__ wqkv,
    unsigned short* __restrict__ qws, unsigned short* __restrict__ kws,
    unsigned short* __restrict__ vt)
{
  const int tid = threadIdx.x;
  const int w = tid >> 6, lane = tid & 63;
  const int l15 = lane & 15, lg = lane >> 4;
  const int wr = w >> 1, wc = w & 1;
  const int bid = blockIdx.x;
  const f32x4 zero = {0.f, 0.f, 0.f, 0.f};
  f32x4 acc[4][4];
  #pragma unroll
  for (int i = 0; i < 4; ++i)
    #pragma unroll
    for (int j = 0; j < 4; ++j) acc[i][j] = zero;

  if (bid < 4096) {
    const int mt = bid & 3;          // e-tile (128 rows)
    const long n0 = (long)(bid >> 2) * 128 + wc * 64;
    const int e_base = mt * 128 + wr * 64;
    #pragma unroll
    for (int ks = 0; ks < 6; ++ks) {
      const int kc = ks * 32 + lg * 8;
      bf16x8 a[4], b[4];
      #pragma unroll
      for (int mi = 0; mi < 4; ++mi)
        a[mi] = *(const bf16x8*)(wqkv + (e_base + mi * 16 + l15) * 192 + kc);
      #pragma unroll
      for (int ni = 0; ni < 4; ++ni)
        b[ni] = *(const bf16x8*)(xt + (n0 + ni * 16 + l15) * 192 + kc);
      #pragma unroll
      for (int mi = 0; mi < 4; ++mi)
        #pragma unroll
        for (int ni = 0; ni < 4; ++ni)
          acc[mi][ni] = MFMA(a[mi], b[ni], acc[mi][ni]);
    }
    #pragma unroll
    for (int ni = 0; ni < 4; ++ni) {
      long tg = n0 + ni * 16 + l15;
      int win = (int)(tg >> 6), tq = (int)(tg & 63);
      if (tq < 49) {
        #pragma unroll
        for (int mi = 0; mi < 4; ++mi) {
          int e0 = e_base + mi * 16 + lg * 4;
          unsigned short* dst = (e0 < 256) ? qws : kws;
          int e = e0 & 255;
          uint2 v = {pk2(acc[mi][ni][0], acc[mi][ni][1]),
                     pk2(acc[mi][ni][2], acc[mi][ni][3])};
          *(uint2*)(dst + ((long)win * 49 + tq) * 256 + e) = v;
        }
      }
    }
  } else {
    const int vb = bid - 4096;
    const long t0 = (long)(vb >> 1) * 128 + wr * 64;
    const int e_n0 = (vb & 1) * 128 + wc * 64;
    #pragma unroll
    for (int ks = 0; ks < 6; ++ks) {
      const int kc = ks * 32 + lg * 8;
      bf16x8 a[4], b[4];
      #pragma unroll
      for (int mi = 0; mi < 4; ++mi)
        a[mi] = *(const bf16x8*)(xt + (t0 + mi * 16 + l15) * 192 + kc);
      #pragma unroll
      for (int ni = 0; ni < 4; ++ni)
        b[ni] = *(const bf16x8*)(wqkv + (512 + e_n0 + ni * 16 + l15) * 192 + kc);
      #pragma unroll
      for (int mi = 0; mi < 4; ++mi)
        #pragma unroll
        for (int ni = 0; ni < 4; ++ni)
          acc[mi][ni] = MFMA(a[mi], b[ni], acc[mi][ni]);
    }
    #pragma unroll
    for (int mi = 0; mi < 4; ++mi) {
      long tg = t0 + mi * 16 + lg * 4;
      int win = (int)(tg >> 6), tl = (int)(tg & 63);
      #pragma unroll
      for (int ni = 0; ni < 4; ++ni) {
        int e = e_n0 + ni * 16 + l15;
        uint2 v = {pk2(acc[mi][ni][0], acc[mi][ni][1]),
                   pk2(acc[mi][ni][2], acc[mi][ni][3])};
        *(uint2*)(vt + ((long)win * 256 + e) * 64 + tl) = v;
      }
    }
  }
}

// ================= K3: attention + output projection =================
// LDS: O [64t][256e] bf16 swz @0 (32KB); P per-wave [64][64] bf16 swz @32768 (8KB each);
//      obuf f32 [49][196] aliases P region after barrier.
#define OLDS 0
#define PLDS 32768
#define LDS_TOT 98304

__global__ __launch_bounds__(512, 2) void la_attn(
    const unsigned short* __restrict__ qws, const unsigned short* __restrict__ kws,
    const unsigned short* __restrict__ vt, const unsigned short* __restrict__ wo,
    const float* __restrict__ bias, const float* __restrict__ bo,
    float* __restrict__ attn_out, float* __restrict__ out)
{
  __shared__ __align__(16) char lds[LDS_TOT];
  const int tid = threadIdx.x;
  const int w = tid >> 6, lane = tid & 63;
  const int l15 = lane & 15, lg = lane >> 4;
  const int win = blockIdx.x;
  const int bi = win >> 6, w1 = (win >> 3) & 7, w2 = win & 7;
  const f32x4 zero = {0.f, 0.f, 0.f, 0.f};
  const int h = w;

  // ---- S = K.Q^T ----
  f32x4 s[4][4];
  {
    const long qkb = (long)win * 49 * 256 + h * 32 + lg * 8;
    bf16x8 ak[4], bq[4];
    #pragma unroll
    for (int mi = 0; mi < 4; ++mi)
      ak[mi] = *(const bf16x8*)(kws + qkb + (mi * 16 + l15) * 256);
    #pragma unroll
    for (int ni = 0; ni < 4; ++ni)
      bq[ni] = *(const bf16x8*)(qws + qkb + (ni * 16 + l15) * 256);
    #pragma unroll
    for (int mi = 0; mi < 4; ++mi)
      #pragma unroll
      for (int ni = 0; ni < 4; ++ni)
        s[mi][ni] = MFMA(ak[mi], bq[ni], zero);
  }

  // ---- softmax over tk (rows) per tq (col) ----
  const float scale = 0.17677669529663687f;
  #pragma unroll
  for (int ni = 0; ni < 4; ++ni) {
    int tq = ni * 16 + l15;
    int tqc = tq < 49 ? tq : 48;
    #pragma unroll
    for (int mi = 0; mi < 4; ++mi)
      #pragma unroll
      for (int r = 0; r < 4; ++r) {
        int tk = mi * 16 + lg * 4 + r;
        float v = s[mi][ni][r];
        s[mi][ni][r] = (tk < 49) ? (v * scale + bias[tqc * 49 + tk]) : -1e30f;
      }
    float m = -1e30f;
    #pragma unroll
    for (int mi = 0; mi < 4; ++mi)
      #pragma unroll
      for (int r = 0; r < 4; ++r) m = fmaxf(m, s[mi][ni][r]);
    m = fmaxf(m, __shfl_xor(m, 16));
    m = fmaxf(m, __shfl_xor(m, 32));
    float sum = 0.f;
    #pragma unroll
    for (int mi = 0; mi < 4; ++mi)
      #pragma unroll
      for (int r = 0; r < 4; ++r) {
        float e = __expf(s[mi][ni][r] - m);
        s[mi][ni][r] = e;
        sum += e;
      }
    sum += __shfl_xor(sum, 16);
    sum += __shfl_xor(sum, 32);
    float inv = 1.0f / sum;
    #pragma unroll
    for (int mi = 0; mi < 4; ++mi)
      #pragma unroll
      for (int r = 0; r < 4; ++r) s[mi][ni][r] *= inv;
  }

  // ---- attn out straight from regs (rows tq, 4..16B runs) ----
  {
    float* abase = attn_out + ((long)win * 8 + h) * 2401;
    #pragma unroll
    for (int ni = 0; ni < 4; ++ni) {
      int tq = ni * 16 + l15;
      if (tq < 49) {
        float* arow = abase + tq * 49;
        #pragma unroll
        for (int mi = 0; mi < 4; ++mi) {
          int tk0 = mi * 16 + lg * 4;
          if (tk0 + 3 < 49)      *(f32x4u*)(arow + tk0) = s[mi][ni];
          else if (tk0 < 49)     arow[tk0] = s[mi][ni][0];
        }
      }
    }
  }

  // ---- P -> wave-private LDS (bf16, swizzled) ----
  {
    char* pw = lds + PLDS + w * 8192;
    #pragma unroll
    for (int ni = 0; ni < 4; ++ni) {
      int tq = ni * 16 + l15;
      #pragma unroll
      for (int mi = 0; mi < 4; ++mi) {
        int tk0 = mi * 16 + lg * 4;
        uint2 v = {pk2(s[mi][ni][0], s[mi][ni][1]),
                   pk2(s[mi][ni][2], s[mi][ni][3])};
        *(uint2*)(pw + tq * 128 + ((tk0 * 2) ^ ((tq & 7) << 4))) = v;
      }
    }
  }

  // ---- O = Vt.P^T (wave-private, no barrier needed) ----
  {
    f32x4 o[2][4];
    #pragma unroll
    for (int i = 0; i < 2; ++i)
      #pragma unroll
      for (int j = 0; j < 4; ++j) o[i][j] = zero;
    const char* pw = lds + PLDS + w * 8192;
    #pragma unroll
    for (int ks = 0; ks < 2; ++ks) {
      const int tkc = ks * 32 + lg * 8;
      bf16x8 av[2], bp[4];
      #pragma unroll
      for (int mi = 0; mi < 2; ++mi) {
        int e = h * 32 + mi * 16 + l15;
        av[mi] = *(const bf16x8*)(vt + ((long)win * 256 + e) * 64 + tkc);
      }
      #pragma unroll
      for (int ni = 0; ni < 4; ++ni) {
        int tq = ni * 16 + l15;
        bp[ni] = *(const bf16x8*)(pw + tq * 128 + ((tkc * 2) ^ ((tq & 7) << 4)));
      }
      #pragma unroll
      for (int mi = 0; mi < 2; ++mi)
        #pragma unroll
        for (int ni = 0; ni < 4; ++ni)
          o[mi][ni] = MFMA(av[mi], bp[ni], o[mi][ni]);
    }
    #pragma unroll
    for (int mi = 0; mi < 2; ++mi)
      #pragma unroll
      for (int ni = 0; ni < 4; ++ni) {
        int tq = ni * 16 + l15;
        int e0 = h * 32 + mi * 16 + lg * 4;
        uint2 v = {pk2(o[mi][ni][0], o[mi][ni][1]),
                   pk2(o[mi][ni][2], o[mi][ni][3])};
        *(uint2*)(lds + OLDS + tq * 512 + ((e0 * 2) ^ ((tq & 7) << 4))) = v;
      }
  }
  __syncthreads();  // all heads' O visible; P dead -> obuf may alias

  // ---- out-proj D[oc][t] = Wo[oc][e] x O[t][e]^T ----
  {
    f32x4 po[6];
    #pragma unroll
    for (int q = 0; q < 6; ++q) po[q] = zero;
    const int id0 = w * 6;
    const int oct0 = id0 >> 2;
    #pragma unroll
    for (int ks = 0; ks < 8; ++ks) {
      const int ec = ks * 32 + lg * 8;
      bf16x8 a2[2], bO[4];
      #pragma unroll
      for (int i = 0; i < 2; ++i)
        a2[i] = *(const bf16x8*)(wo + ((oct0 + i) * 16 + l15) * 256 + ec);
      #pragma unroll
      for (int tt = 0; tt < 4; ++tt) {
        int t = tt * 16 + l15;
        bO[tt] = *(const bf16x8*)(lds + OLDS + t * 512 + ((ec * 2) ^ ((t & 7) << 4)));
      }
      #pragma unroll
      for (int q = 0; q < 6; ++q) {
        int id = id0 + q;
        po[q] = MFMA(a2[(id >> 2) - oct0], bO[id & 3], po[q]);
      }
    }
    __syncthreads();  // P reads done everywhere (already, via prior barrier); obuf writes ordered
    float* obuf = (float*)(lds + PLDS);
    #pragma unroll
    for (int q = 0; q < 6; ++q) {
      int id = id0 + q;
      int oc0 = (id >> 2) * 16 + lg * 4;
      int t = (id & 3) * 16 + l15;
      if (t < 49)
        *(f32x4*)(obuf + t * 196 + oc0) = po[q];
    }
  }
  __syncthreads();

  // ---- final scatter write (+bo) ----
  {
    const float* obuf = (const float*)(lds + PLDS);
    const long obase = (long)bi * 602112 + (w1 * 7) * 56 + w2 * 7;
    for (int idx = tid; idx < 192 * 49; idx += 512) {
      int oc = idx / 49, t = idx - oc * 49;
      out[obase + oc * 3136 + (t / 7) * 56 + (t % 7)] = obuf[t * 196 + oc] + bo[oc];
    }
  }
}

extern "C" void kernel_launch(void* const* d_in, const int* in_sizes, int n_in,
                              void* d_out, int out_size, void* d_ws, size_t ws_size,
                              hipStream_t stream)
{
  const float* x    = (const float*)d_in[0];
  const float* mask = (const float*)d_in[1];
  const float* Wq   = (const float*)d_in[2];
  const float* Wkv  = (const float*)d_in[3];
  const float* Wo   = (const float*)d_in[4];
  const float* bo   = (const float*)d_in[5];
  const float* pos  = (const float*)d_in[6];

  float* out  = (float*)d_out;
  float* attn = out + OUT0;

  char* ws = (char*)d_ws;
  unsigned short* xt   = (unsigned short*)ws;
  unsigned short* qws  = (unsigned short*)(ws + Q_OFF);
  unsigned short* kws  = (unsigned short*)(ws + K_OFF);
  unsigned short* vt   = (unsigned short*)(ws + V_OFF);
  unsigned short* wqkv = (unsigned short*)(ws + WQKV_OFF);
  unsigned short* wo   = (unsigned short*)(ws + WO_OFF);
  float*          bias = (float*)(ws + BIAS_OFF);

  xt_prep<<<NWIN, 256, 0, stream>>>(x, mask, Wq, Wkv, Wo, pos, xt, wqkv, wo, bias);
  qkvv_gemm<<<6144, 256, 0, stream>>>(xt, wqkv, qws, kws, vt);
  la_attn<<<NWIN, 512, 0, stream>>>(qws, kws, vt, wo, bias, bo, attn, out);
}

// Round 4
// 411.035 us; speedup vs baseline: 14.1710x; 14.1710x over previous
//
#include <hip/hip_runtime.h>

// LocalAttention P=7 window attention — split-pipeline bf16 MFMA.
// Round 4: eliminate runtime-indexed MFMA fragment arrays in the Wo-projection
// (rule #20: they spill to scratch -> ~0.5GB/launch private traffic). All
// fragment register indices are now compile-time; runtime values only appear
// in ADDRESSES. Also shrink LDS 98304->75264 (49-row O/P) for 2 blocks/CU.

#define NWIN 2048
#define OUT0 19267584L

typedef __attribute__((ext_vector_type(8))) short bf16x8;
typedef __attribute__((ext_vector_type(4))) float f32x4;
typedef __attribute__((ext_vector_type(4), aligned(4))) float f32x4u;

#define MFMA(a, b, c) __builtin_amdgcn_mfma_f32_16x16x32_bf16(a, b, c, 0, 0, 0)

__device__ __forceinline__ unsigned short f2b(float f) {
  unsigned u = __builtin_bit_cast(unsigned, f);
  return (unsigned short)((u + 0x7FFFu + ((u >> 16) & 1u)) >> 16);
}
__device__ __forceinline__ unsigned pk2(float a, float b) {
  return (unsigned)f2b(a) | ((unsigned)f2b(b) << 16);
}

// ---- workspace layout ----
#define XT_ELEMS   (2048L * 64 * 192)
#define QK_ROWS    (2048L * 49 + 64)
#define Q_OFF      (XT_ELEMS * 2)
#define K_OFF      (Q_OFF + QK_ROWS * 256 * 2)
#define V_OFF      (K_OFF + QK_ROWS * 256 * 2)
#define WQKV_OFF   (V_OFF + 2048L * 256 * 64 * 2)
#define WO_OFF     (WQKV_OFF + 768L * 192 * 2)
#define BIAS_OFF   (WO_OFF + 192L * 256 * 2)

// ================= K1: window transpose + prep =================
__global__ __launch_bounds__(256) void xt_prep(
    const float* __restrict__ x, const float* __restrict__ mask,
    const float* __restrict__ Wq, const float* __restrict__ Wkv,
    const float* __restrict__ Wo, const float* __restrict__ pos,
    unsigned short* __restrict__ xt, unsigned short* __restrict__ wqkv,
    unsigned short* __restrict__ wo, float* __restrict__ bias)
{
  __shared__ float sXw[192][53];
  const int tid = threadIdx.x;
  const int widx = blockIdx.x;
  const int bi = widx >> 6, w1 = (widx >> 3) & 7, w2 = widx & 7;
  const long xbase = (long)bi * 192 * 3136 + (w1 * 7) * 56 + w2 * 7;

  for (int idx = tid; idx < 192 * 49; idx += 256) {
    int c = idx / 49, t = idx - c * 49;
    sXw[c][t] = x[xbase + c * 3136 + (t / 7) * 56 + (t % 7)];
  }
  {
    int gid = widx * 256 + tid;
    if (gid < 147456)       wqkv[gid] = f2b(gid < 49152 ? Wq[gid] : Wkv[gid - 49152]);
    else if (gid < 196608)  { int i = gid - 147456; wo[i] = f2b(Wo[i]); }
    else if (gid < 199009)  {
      int i = gid - 196608;
      int tq = i / 49, tk = i - tq * 49;
      int r0 = tk / 7 - tq / 7 + 6, r1 = tk % 7 - tq % 7 + 6;
      bias[i] = mask[i] + pos[r0 * 13 + r1];
    }
  }
  __syncthreads();
  unsigned short* xw = xt + (long)widx * 64 * 192;
  for (int idx = tid; idx < 64 * 192; idx += 256) {
    int t = idx / 192, c = idx - t * 192;
    xw[idx] = (t < 49) ? f2b(sXw[c][t]) : (unsigned short)0;
  }
}

// ================= K2: QKV GEMMs (no LDS, direct frags) =================
__global__ __launch_bounds__(256, 3) void qkvv_gemm(
    const unsigned short* __restrict__ xt, const unsigned short* __restrict__ wqkv,
    unsigned short* __restrict__ qws, unsigned short* __restrict__ kws,
    unsigned short* __restrict__ vt)
{
  const int tid = threadIdx.x;
  const int w = tid >> 6, lane = tid & 63;
  const int l15 = lane & 15, lg = lane >> 4;
  const int wr = w >> 1, wc = w & 1;
  const int bid = blockIdx.x;
  const f32x4 zero = {0.f, 0.f, 0.f, 0.f};
  f32x4 acc[4][4];
  #pragma unroll
  for (int i = 0; i < 4; ++i)
    #pragma unroll
    for (int j = 0; j < 4; ++j) acc[i][j] = zero;

  if (bid < 4096) {
    const int mt = bid & 3;
    const long n0 = (long)(bid >> 2) * 128 + wc * 64;
    const int e_base = mt * 128 + wr * 64;
    #pragma unroll
    for (int ks = 0; ks < 6; ++ks) {
      const int kc = ks * 32 + lg * 8;
      bf16x8 a[4], b[4];
      #pragma unroll
      for (int mi = 0; mi < 4; ++mi)
        a[mi] = *(const bf16x8*)(wqkv + (e_base + mi * 16 + l15) * 192 + kc);
      #pragma unroll
      for (int ni = 0; ni < 4; ++ni)
        b[ni] = *(const bf16x8*)(xt + (n0 + ni * 16 + l15) * 192 + kc);
      #pragma unroll
      for (int mi = 0; mi < 4; ++mi)
        #pragma unroll
        for (int ni = 0; ni < 4; ++ni)
          acc[mi][ni] = MFMA(a[mi], b[ni], acc[mi][ni]);
    }
    #pragma unroll
    for (int ni = 0; ni < 4; ++ni) {
      long tg = n0 + ni * 16 + l15;
      int win = (int)(tg >> 6), tq = (int)(tg & 63);
      if (tq < 49) {
        #pragma unroll
        for (int mi = 0; mi < 4; ++mi) {
          int e0 = e_base + mi * 16 + lg * 4;
          unsigned short* dst = (e0 < 256) ? qws : kws;
          int e = e0 & 255;
          uint2 v = {pk2(acc[mi][ni][0], acc[mi][ni][1]),
                     pk2(acc[mi][ni][2], acc[mi][ni][3])};
          *(uint2*)(dst + ((long)win * 49 + tq) * 256 + e) = v;
        }
      }
    }
  } else {
    const int vb = bid - 4096;
    const long t0 = (long)(vb >> 1) * 128 + wr * 64;
    const int e_n0 = (vb & 1) * 128 + wc * 64;
    #pragma unroll
    for (int ks = 0; ks < 6; ++ks) {
      const int kc = ks * 32 + lg * 8;
      bf16x8 a[4], b[4];
      #pragma unroll
      for (int mi = 0; mi < 4; ++mi)
        a[mi] = *(const bf16x8*)(xt + (t0 + mi * 16 + l15) * 192 + kc);
      #pragma unroll
      for (int ni = 0; ni < 4; ++ni)
        b[ni] = *(const bf16x8*)(wqkv + (512 + e_n0 + ni * 16 + l15) * 192 + kc);
      #pragma unroll
      for (int mi = 0; mi < 4; ++mi)
        #pragma unroll
        for (int ni = 0; ni < 4; ++ni)
          acc[mi][ni] = MFMA(a[mi], b[ni], acc[mi][ni]);
    }
    #pragma unroll
    for (int mi = 0; mi < 4; ++mi) {
      long tg = t0 + mi * 16 + lg * 4;
      int win = (int)(tg >> 6), tl = (int)(tg & 63);
      #pragma unroll
      for (int ni = 0; ni < 4; ++ni) {
        int e = e_n0 + ni * 16 + l15;
        uint2 v = {pk2(acc[mi][ni][0], acc[mi][ni][1]),
                   pk2(acc[mi][ni][2], acc[mi][ni][3])};
        *(uint2*)(vt + ((long)win * 256 + e) * 64 + tl) = v;
      }
    }
  }
}

// ================= K3: attention + output projection =================
// LDS: O [49t][256e] bf16 swz @0 (25088B); P per-wave [49][64] bf16 swz
//      @25088 (6272B/wave, 50176B total); obuf f32 [49][196] aliases P.
// Total 75264B -> 2 blocks/CU.
#define OLDS 0
#define PLDS 25088
#define PSTRIDE 6272
#define LDS_TOT 75264

__global__ __launch_bounds__(512, 2) void la_attn(
    const unsigned short* __restrict__ qws, const unsigned short* __restrict__ kws,
    const unsigned short* __restrict__ vt, const unsigned short* __restrict__ wo,
    const float* __restrict__ bias, const float* __restrict__ bo,
    float* __restrict__ attn_out, float* __restrict__ out)
{
  __shared__ __align__(16) char lds[LDS_TOT];
  const int tid = threadIdx.x;
  const int w = tid >> 6, lane = tid & 63;
  const int l15 = lane & 15, lg = lane >> 4;
  const int win = blockIdx.x;
  const int bi = win >> 6, w1 = (win >> 3) & 7, w2 = win & 7;
  const f32x4 zero = {0.f, 0.f, 0.f, 0.f};
  const int h = w;

  // ---- S = K.Q^T ----
  f32x4 s[4][4];
  {
    const long qkb = (long)win * 49 * 256 + h * 32 + lg * 8;
    bf16x8 ak[4], bq[4];
    #pragma unroll
    for (int mi = 0; mi < 4; ++mi)
      ak[mi] = *(const bf16x8*)(kws + qkb + (mi * 16 + l15) * 256);
    #pragma unroll
    for (int ni = 0; ni < 4; ++ni)
      bq[ni] = *(const bf16x8*)(qws + qkb + (ni * 16 + l15) * 256);
    #pragma unroll
    for (int mi = 0; mi < 4; ++mi)
      #pragma unroll
      for (int ni = 0; ni < 4; ++ni)
        s[mi][ni] = MFMA(ak[mi], bq[ni], zero);
  }

  // ---- softmax over tk per tq-column ----
  const float scale = 0.17677669529663687f;
  #pragma unroll
  for (int ni = 0; ni < 4; ++ni) {
    int tq = ni * 16 + l15;
    int tqc = tq < 49 ? tq : 48;
    #pragma unroll
    for (int mi = 0; mi < 4; ++mi)
      #pragma unroll
      for (int r = 0; r < 4; ++r) {
        int tk = mi * 16 + lg * 4 + r;
        float v = s[mi][ni][r];
        s[mi][ni][r] = (tk < 49) ? (v * scale + bias[tqc * 49 + tk]) : -1e30f;
      }
    float m = -1e30f;
    #pragma unroll
    for (int mi = 0; mi < 4; ++mi)
      #pragma unroll
      for (int r = 0; r < 4; ++r) m = fmaxf(m, s[mi][ni][r]);
    m = fmaxf(m, __shfl_xor(m, 16));
    m = fmaxf(m, __shfl_xor(m, 32));
    float sum = 0.f;
    #pragma unroll
    for (int mi = 0; mi < 4; ++mi)
      #pragma unroll
      for (int r = 0; r < 4; ++r) {
        float e = __expf(s[mi][ni][r] - m);
        s[mi][ni][r] = e;
        sum += e;
      }
    sum += __shfl_xor(sum, 16);
    sum += __shfl_xor(sum, 32);
    float inv = 1.0f / sum;
    #pragma unroll
    for (int mi = 0; mi < 4; ++mi)
      #pragma unroll
      for (int r = 0; r < 4; ++r) s[mi][ni][r] *= inv;
  }

  // ---- attn out straight from regs ----
  {
    float* abase = attn_out + ((long)win * 8 + h) * 2401;
    #pragma unroll
    for (int ni = 0; ni < 4; ++ni) {
      int tq = ni * 16 + l15;
      if (tq < 49) {
        float* arow = abase + tq * 49;
        #pragma unroll
        for (int mi = 0; mi < 4; ++mi) {
          int tk0 = mi * 16 + lg * 4;
          if (tk0 + 3 < 49)      *(f32x4u*)(arow + tk0) = s[mi][ni];
          else if (tk0 < 49)     arow[tk0] = s[mi][ni][0];
        }
      }
    }
  }

  // ---- P -> wave-private LDS (bf16, swizzled, 49 rows) ----
  {
    char* pw = lds + PLDS + w * PSTRIDE;
    #pragma unroll
    for (int ni = 0; ni < 4; ++ni) {
      int tq = ni * 16 + l15;
      if (tq < 49) {
        #pragma unroll
        for (int mi = 0; mi < 4; ++mi) {
          int tk0 = mi * 16 + lg * 4;
          uint2 v = {pk2(s[mi][ni][0], s[mi][ni][1]),
                     pk2(s[mi][ni][2], s[mi][ni][3])};
          *(uint2*)(pw + tq * 128 + ((tk0 * 2) ^ ((tq & 7) << 4))) = v;
        }
      }
    }
  }

  // ---- O = Vt.P^T (wave-private P, no barrier needed) ----
  {
    f32x4 o[2][4];
    #pragma unroll
    for (int i = 0; i < 2; ++i)
      #pragma unroll
      for (int j = 0; j < 4; ++j) o[i][j] = zero;
    const char* pw = lds + PLDS + w * PSTRIDE;
    #pragma unroll
    for (int ks = 0; ks < 2; ++ks) {
      const int tkc = ks * 32 + lg * 8;
      bf16x8 av[2], bp[4];
      #pragma unroll
      for (int mi = 0; mi < 2; ++mi) {
        int e = h * 32 + mi * 16 + l15;
        av[mi] = *(const bf16x8*)(vt + ((long)win * 256 + e) * 64 + tkc);
      }
      #pragma unroll
      for (int ni = 0; ni < 4; ++ni) {
        int tq = ni * 16 + l15;
        int tqc = tq < 49 ? tq : 48;
        bp[ni] = *(const bf16x8*)(pw + tqc * 128 + ((tkc * 2) ^ ((tqc & 7) << 4)));
      }
      #pragma unroll
      for (int mi = 0; mi < 2; ++mi)
        #pragma unroll
        for (int ni = 0; ni < 4; ++ni)
          o[mi][ni] = MFMA(av[mi], bp[ni], o[mi][ni]);
    }
    #pragma unroll
    for (int mi = 0; mi < 2; ++mi)
      #pragma unroll
      for (int ni = 0; ni < 4; ++ni) {
        int tq = ni * 16 + l15;
        if (tq < 49) {
          int e0 = h * 32 + mi * 16 + lg * 4;
          uint2 v = {pk2(o[mi][ni][0], o[mi][ni][1]),
                     pk2(o[mi][ni][2], o[mi][ni][3])};
          *(uint2*)(lds + OLDS + tq * 512 + ((e0 * 2) ^ ((tq & 7) << 4))) = v;
        }
      }
  }
  __syncthreads();  // O visible to all waves; P dead -> obuf may alias P

  // ---- out-proj D[oc][t] = Wo[oc][e] x O[t][e]^T ----
  // wave w: fixed t-tile (w&3), oc-tiles (w>>2)*6 + j (j=0..5).
  // ALL fragment register indices compile-time (no scratch).
  {
    f32x4 po[6];
    #pragma unroll
    for (int q = 0; q < 6; ++q) po[q] = zero;
    const int tt = w & 3;
    const int og = (w >> 2) * 6;
    const int tO = tt * 16 + l15;
    const int tOc = tO < 49 ? tO : 48;
    #pragma unroll
    for (int ks = 0; ks < 8; ++ks) {
      const int ec = ks * 32 + lg * 8;
      bf16x8 bO = *(const bf16x8*)(lds + OLDS + tOc * 512 + ((ec * 2) ^ ((tOc & 7) << 4)));
      #pragma unroll
      for (int j = 0; j < 6; ++j) {
        bf16x8 aW = *(const bf16x8*)(wo + ((og + j) * 16 + l15) * 256 + ec);
        po[j] = MFMA(aW, bO, po[j]);
      }
    }
    float* obuf = (float*)(lds + PLDS);
    #pragma unroll
    for (int j = 0; j < 6; ++j) {
      int oc0 = (og + j) * 16 + lg * 4;
      if (tO < 49) *(f32x4*)(obuf + tO * 196 + oc0) = po[j];
    }
  }
  __syncthreads();

  // ---- final scatter write (+bo) ----
  {
    const float* obuf = (const float*)(lds + PLDS);
    const long obase = (long)bi * 602112 + (w1 * 7) * 56 + w2 * 7;
    for (int idx = tid; idx < 192 * 49; idx += 512) {
      int oc = idx / 49, t = idx - oc * 49;
      out[obase + oc * 3136 + (t / 7) * 56 + (t % 7)] = obuf[t * 196 + oc] + bo[oc];
    }
  }
}

extern "C" void kernel_launch(void* const* d_in, const int* in_sizes, int n_in,
                              void* d_out, int out_size, void* d_ws, size_t ws_size,
                              hipStream_t stream)
{
  const float* x    = (const float*)d_in[0];
  const float* mask = (const float*)d_in[1];
  const float* Wq   = (const float*)d_in[2];
  const float* Wkv  = (const float*)d_in[3];
  const float* Wo   = (const float*)d_in[4];
  const float* bo   = (const float*)d_in[5];
  const float* pos  = (const float*)d_in[6];

  float* out  = (float*)d_out;
  float* attn = out + OUT0;

  char* ws = (char*)d_ws;
  unsigned short* xt   = (unsigned short*)ws;
  unsigned short* qws  = (unsigned short*)(ws + Q_OFF);
  unsigned short* kws  = (unsigned short*)(ws + K_OFF);
  unsigned short* vt   = (unsigned short*)(ws + V_OFF);
  unsigned short* wqkv = (unsigned short*)(ws + WQKV_OFF);
  unsigned short* wo   = (unsigned short*)(ws + WO_OFF);
  float*          bias = (float*)(ws + BIAS_OFF);

  xt_prep<<<NWIN, 256, 0, stream>>>(x, mask, Wq, Wkv, Wo, pos, xt, wqkv, wo, bias);
  qkvv_gemm<<<6144, 256, 0, stream>>>(xt, wqkv, qws, kws, vt);
  la_attn<<<NWIN, 512, 0, stream>>>(qws, kws, vt, wo, bias, bo, attn, out);
}

// Round 5
// 410.793 us; speedup vs baseline: 14.1794x; 1.0006x over previous
//
#include <hip/hip_runtime.h>

// LocalAttention P=7 window attention — split-pipeline bf16 MFMA.
// Round 5: coalesce the attn-probability store. It was 157MB of f32x4 stores
// at stride-196B (partial-line RMW, WRITE_SIZE 307 vs 234 mandatory). Now each
// wave streams its own head's P row-major from LDS (full 64B lines), issued
// before the PV MFMAs so stores overlap compute. One barrier removed.

#define NWIN 2048
#define OUT0 19267584L

typedef __attribute__((ext_vector_type(8))) short bf16x8;
typedef __attribute__((ext_vector_type(4))) float f32x4;

#define MFMA(a, b, c) __builtin_amdgcn_mfma_f32_16x16x32_bf16(a, b, c, 0, 0, 0)

__device__ __forceinline__ unsigned short f2b(float f) {
  unsigned u = __builtin_bit_cast(unsigned, f);
  return (unsigned short)((u + 0x7FFFu + ((u >> 16) & 1u)) >> 16);
}
__device__ __forceinline__ unsigned pk2(float a, float b) {
  return (unsigned)f2b(a) | ((unsigned)f2b(b) << 16);
}
__device__ __forceinline__ float b2f(unsigned short h) {
  unsigned u = ((unsigned)h) << 16;
  return __builtin_bit_cast(float, u);
}

// ---- workspace layout ----
#define XT_ELEMS   (2048L * 64 * 192)
#define QK_ROWS    (2048L * 49 + 64)
#define Q_OFF      (XT_ELEMS * 2)
#define K_OFF      (Q_OFF + QK_ROWS * 256 * 2)
#define V_OFF      (K_OFF + QK_ROWS * 256 * 2)
#define WQKV_OFF   (V_OFF + 2048L * 256 * 64 * 2)
#define WO_OFF     (WQKV_OFF + 768L * 192 * 2)
#define BIAS_OFF   (WO_OFF + 192L * 256 * 2)

// ================= K1: window transpose + prep =================
__global__ __launch_bounds__(256) void xt_prep(
    const float* __restrict__ x, const float* __restrict__ mask,
    const float* __restrict__ Wq, const float* __restrict__ Wkv,
    const float* __restrict__ Wo, const float* __restrict__ pos,
    unsigned short* __restrict__ xt, unsigned short* __restrict__ wqkv,
    unsigned short* __restrict__ wo, float* __restrict__ bias)
{
  __shared__ float sXw[192][53];
  const int tid = threadIdx.x;
  const int widx = blockIdx.x;
  const int bi = widx >> 6, w1 = (widx >> 3) & 7, w2 = widx & 7;
  const long xbase = (long)bi * 192 * 3136 + (w1 * 7) * 56 + w2 * 7;

  for (int idx = tid; idx < 192 * 49; idx += 256) {
    int c = idx / 49, t = idx - c * 49;
    sXw[c][t] = x[xbase + c * 3136 + (t / 7) * 56 + (t % 7)];
  }
  {
    int gid = widx * 256 + tid;
    if (gid < 147456)       wqkv[gid] = f2b(gid < 49152 ? Wq[gid] : Wkv[gid - 49152]);
    else if (gid < 196608)  { int i = gid - 147456; wo[i] = f2b(Wo[i]); }
    else if (gid < 199009)  {
      int i = gid - 196608;
      int tq = i / 49, tk = i - tq * 49;
      int r0 = tk / 7 - tq / 7 + 6, r1 = tk % 7 - tq % 7 + 6;
      bias[i] = mask[i] + pos[r0 * 13 + r1];
    }
  }
  __syncthreads();
  unsigned short* xw = xt + (long)widx * 64 * 192;
  for (int idx = tid; idx < 64 * 192; idx += 256) {
    int t = idx / 192, c = idx - t * 192;
    xw[idx] = (t < 49) ? f2b(sXw[c][t]) : (unsigned short)0;
  }
}

// ================= K2: QKV GEMMs (no LDS, direct frags) =================
__global__ __launch_bounds__(256, 3) void qkvv_gemm(
    const unsigned short* __restrict__ xt, const unsigned short* __restrict__ wqkv,
    unsigned short* __restrict__ qws, unsigned short* __restrict__ kws,
    unsigned short* __restrict__ vt)
{
  const int tid = threadIdx.x;
  const int w = tid >> 6, lane = tid & 63;
  const int l15 = lane & 15, lg = lane >> 4;
  const int wr = w >> 1, wc = w & 1;
  const int bid = blockIdx.x;
  const f32x4 zero = {0.f, 0.f, 0.f, 0.f};
  f32x4 acc[4][4];
  #pragma unroll
  for (int i = 0; i < 4; ++i)
    #pragma unroll
    for (int j = 0; j < 4; ++j) acc[i][j] = zero;

  if (bid < 4096) {
    const int mt = bid & 3;
    const long n0 = (long)(bid >> 2) * 128 + wc * 64;
    const int e_base = mt * 128 + wr * 64;
    #pragma unroll
    for (int ks = 0; ks < 6; ++ks) {
      const int kc = ks * 32 + lg * 8;
      bf16x8 a[4], b[4];
      #pragma unroll
      for (int mi = 0; mi < 4; ++mi)
        a[mi] = *(const bf16x8*)(wqkv + (e_base + mi * 16 + l15) * 192 + kc);
      #pragma unroll
      for (int ni = 0; ni < 4; ++ni)
        b[ni] = *(const bf16x8*)(xt + (n0 + ni * 16 + l15) * 192 + kc);
      #pragma unroll
      for (int mi = 0; mi < 4; ++mi)
        #pragma unroll
        for (int ni = 0; ni < 4; ++ni)
          acc[mi][ni] = MFMA(a[mi], b[ni], acc[mi][ni]);
    }
    #pragma unroll
    for (int ni = 0; ni < 4; ++ni) {
      long tg = n0 + ni * 16 + l15;
      int win = (int)(tg >> 6), tq = (int)(tg & 63);
      if (tq < 49) {
        #pragma unroll
        for (int mi = 0; mi < 4; ++mi) {
          int e0 = e_base + mi * 16 + lg * 4;
          unsigned short* dst = (e0 < 256) ? qws : kws;
          int e = e0 & 255;
          uint2 v = {pk2(acc[mi][ni][0], acc[mi][ni][1]),
                     pk2(acc[mi][ni][2], acc[mi][ni][3])};
          *(uint2*)(dst + ((long)win * 49 + tq) * 256 + e) = v;
        }
      }
    }
  } else {
    const int vb = bid - 4096;
    const long t0 = (long)(vb >> 1) * 128 + wr * 64;
    const int e_n0 = (vb & 1) * 128 + wc * 64;
    #pragma unroll
    for (int ks = 0; ks < 6; ++ks) {
      const int kc = ks * 32 + lg * 8;
      bf16x8 a[4], b[4];
      #pragma unroll
      for (int mi = 0; mi < 4; ++mi)
        a[mi] = *(const bf16x8*)(xt + (t0 + mi * 16 + l15) * 192 + kc);
      #pragma unroll
      for (int ni = 0; ni < 4; ++ni)
        b[ni] = *(const bf16x8*)(wqkv + (512 + e_n0 + ni * 16 + l15) * 192 + kc);
      #pragma unroll
      for (int mi = 0; mi < 4; ++mi)
        #pragma unroll
        for (int ni = 0; ni < 4; ++ni)
          acc[mi][ni] = MFMA(a[mi], b[ni], acc[mi][ni]);
    }
    #pragma unroll
    for (int mi = 0; mi < 4; ++mi) {
      long tg = t0 + mi * 16 + lg * 4;
      int win = (int)(tg >> 6), tl = (int)(tg & 63);
      #pragma unroll
      for (int ni = 0; ni < 4; ++ni) {
        int e = e_n0 + ni * 16 + l15;
        uint2 v = {pk2(acc[mi][ni][0], acc[mi][ni][1]),
                   pk2(acc[mi][ni][2], acc[mi][ni][3])};
        *(uint2*)(vt + ((long)win * 256 + e) * 64 + tl) = v;
      }
    }
  }
}

// ================= K3: attention + output projection =================
// LDS: O [49t][256e] bf16 swz @0 (25088B); P per-wave [49][64] bf16 swz
//      @25088 (6272B/wave); obuf f32 [49][196] aliases P after barrier.
// Total 75264B -> 2 blocks/CU.
#define OLDS 0
#define PLDS 25088
#define PSTRIDE 6272
#define LDS_TOT 75264

__global__ __launch_bounds__(512, 2) void la_attn(
    const unsigned short* __restrict__ qws, const unsigned short* __restrict__ kws,
    const unsigned short* __restrict__ vt, const unsigned short* __restrict__ wo,
    const float* __restrict__ bias, const float* __restrict__ bo,
    float* __restrict__ attn_out, float* __restrict__ out)
{
  __shared__ __align__(16) char lds[LDS_TOT];
  const int tid = threadIdx.x;
  const int w = tid >> 6, lane = tid & 63;
  const int l15 = lane & 15, lg = lane >> 4;
  const int win = blockIdx.x;
  const int bi = win >> 6, w1 = (win >> 3) & 7, w2 = win & 7;
  const f32x4 zero = {0.f, 0.f, 0.f, 0.f};
  const int h = w;

  // ---- S = K.Q^T ----
  f32x4 s[4][4];
  {
    const long qkb = (long)win * 49 * 256 + h * 32 + lg * 8;
    bf16x8 ak[4], bq[4];
    #pragma unroll
    for (int mi = 0; mi < 4; ++mi)
      ak[mi] = *(const bf16x8*)(kws + qkb + (mi * 16 + l15) * 256);
    #pragma unroll
    for (int ni = 0; ni < 4; ++ni)
      bq[ni] = *(const bf16x8*)(qws + qkb + (ni * 16 + l15) * 256);
    #pragma unroll
    for (int mi = 0; mi < 4; ++mi)
      #pragma unroll
      for (int ni = 0; ni < 4; ++ni)
        s[mi][ni] = MFMA(ak[mi], bq[ni], zero);
  }

  // ---- softmax over tk per tq-column ----
  const float scale = 0.17677669529663687f;
  #pragma unroll
  for (int ni = 0; ni < 4; ++ni) {
    int tq = ni * 16 + l15;
    int tqc = tq < 49 ? tq : 48;
    #pragma unroll
    for (int mi = 0; mi < 4; ++mi)
      #pragma unroll
      for (int r = 0; r < 4; ++r) {
        int tk = mi * 16 + lg * 4 + r;
        float v = s[mi][ni][r];
        s[mi][ni][r] = (tk < 49) ? (v * scale + bias[tqc * 49 + tk]) : -1e30f;
      }
    float m = -1e30f;
    #pragma unroll
    for (int mi = 0; mi < 4; ++mi)
      #pragma unroll
      for (int r = 0; r < 4; ++r) m = fmaxf(m, s[mi][ni][r]);
    m = fmaxf(m, __shfl_xor(m, 16));
    m = fmaxf(m, __shfl_xor(m, 32));
    float sum = 0.f;
    #pragma unroll
    for (int mi = 0; mi < 4; ++mi)
      #pragma unroll
      for (int r = 0; r < 4; ++r) {
        float e = __expf(s[mi][ni][r] - m);
        s[mi][ni][r] = e;
        sum += e;
      }
    sum += __shfl_xor(sum, 16);
    sum += __shfl_xor(sum, 32);
    float inv = 1.0f / sum;
    #pragma unroll
    for (int mi = 0; mi < 4; ++mi)
      #pragma unroll
      for (int r = 0; r < 4; ++r) s[mi][ni][r] *= inv;
  }

  // ---- P -> wave-private LDS (bf16, swizzled, 49 rows) ----
  {
    char* pw = lds + PLDS + w * PSTRIDE;
    #pragma unroll
    for (int ni = 0; ni < 4; ++ni) {
      int tq = ni * 16 + l15;
      if (tq < 49) {
        #pragma unroll
        for (int mi = 0; mi < 4; ++mi) {
          int tk0 = mi * 16 + lg * 4;
          uint2 v = {pk2(s[mi][ni][0], s[mi][ni][1]),
                     pk2(s[mi][ni][2], s[mi][ni][3])};
          *(uint2*)(pw + tq * 128 + ((tk0 * 2) ^ ((tq & 7) << 4))) = v;
        }
      }
    }
  }

  // ---- attn out: per-wave coalesced stream of own head from P_lds ----
  // 2401 floats flat; 64 lanes x 4B = 256B/instr, full 64B lines. Issued
  // before PV so the MFMAs below overlap the store latency.
  {
    const char* pw = lds + PLDS + w * PSTRIDE;
    float* abase = attn_out + ((long)win * 8 + h) * 2401;
    #pragma unroll
    for (int it = 0; it < 38; ++it) {
      int f = it * 64 + lane;
      if (f < 2401) {
        int tq = f / 49, tk = f - tq * 49;
        unsigned short pv =
            *(const unsigned short*)(pw + tq * 128 + ((tk * 2) ^ ((tq & 7) << 4)));
        abase[f] = b2f(pv);
      }
    }
  }

  // ---- O = Vt.P^T (wave-private P, no barrier needed) ----
  {
    f32x4 o[2][4];
    #pragma unroll
    for (int i = 0; i < 2; ++i)
      #pragma unroll
      for (int j = 0; j < 4; ++j) o[i][j] = zero;
    const char* pw = lds + PLDS + w * PSTRIDE;
    #pragma unroll
    for (int ks = 0; ks < 2; ++ks) {
      const int tkc = ks * 32 + lg * 8;
      bf16x8 av[2], bp[4];
      #pragma unroll
      for (int mi = 0; mi < 2; ++mi) {
        int e = h * 32 + mi * 16 + l15;
        av[mi] = *(const bf16x8*)(vt + ((long)win * 256 + e) * 64 + tkc);
      }
      #pragma unroll
      for (int ni = 0; ni < 4; ++ni) {
        int tq = ni * 16 + l15;
        int tqc = tq < 49 ? tq : 48;
        bp[ni] = *(const bf16x8*)(pw + tqc * 128 + ((tkc * 2) ^ ((tqc & 7) << 4)));
      }
      #pragma unroll
      for (int mi = 0; mi < 2; ++mi)
        #pragma unroll
        for (int ni = 0; ni < 4; ++ni)
          o[mi][ni] = MFMA(av[mi], bp[ni], o[mi][ni]);
    }
    #pragma unroll
    for (int mi = 0; mi < 2; ++mi)
      #pragma unroll
      for (int ni = 0; ni < 4; ++ni) {
        int tq = ni * 16 + l15;
        if (tq < 49) {
          int e0 = h * 32 + mi * 16 + lg * 4;
          uint2 v = {pk2(o[mi][ni][0], o[mi][ni][1]),
                     pk2(o[mi][ni][2], o[mi][ni][3])};
          *(uint2*)(lds + OLDS + tq * 512 + ((e0 * 2) ^ ((tq & 7) << 4))) = v;
        }
      }
  }
  __syncthreads();  // all O visible; all waves past their P reads -> obuf may alias P

  // ---- out-proj D[oc][t] = Wo[oc][e] x O[t][e]^T ----
  // wave w: fixed t-tile (w&3), oc-tiles (w>>2)*6 + j. All frag indices
  // compile-time (rule #20).
  {
    f32x4 po[6];
    #pragma unroll
    for (int q = 0; q < 6; ++q) po[q] = zero;
    const int tt = w & 3;
    const int og = (w >> 2) * 6;
    const int tO = tt * 16 + l15;
    const int tOc = tO < 49 ? tO : 48;
    #pragma unroll
    for (int ks = 0; ks < 8; ++ks) {
      const int ec = ks * 32 + lg * 8;
      bf16x8 bO = *(const bf16x8*)(lds + OLDS + tOc * 512 + ((ec * 2) ^ ((tOc & 7) << 4)));
      #pragma unroll
      for (int j = 0; j < 6; ++j) {
        bf16x8 aW = *(const bf16x8*)(wo + ((og + j) * 16 + l15) * 256 + ec);
        po[j] = MFMA(aW, bO, po[j]);
      }
    }
    float* obuf = (float*)(lds + PLDS);
    #pragma unroll
    for (int j = 0; j < 6; ++j) {
      int oc0 = (og + j) * 16 + lg * 4;
      if (tO < 49) *(f32x4*)(obuf + tO * 196 + oc0) = po[j];
    }
  }
  __syncthreads();

  // ---- final scatter write (+bo) ----
  {
    const float* obuf = (const float*)(lds + PLDS);
    const long obase = (long)bi * 602112 + (w1 * 7) * 56 + w2 * 7;
    for (int idx = tid; idx < 192 * 49; idx += 512) {
      int oc = idx / 49, t = idx - oc * 49;
      out[obase + oc * 3136 + (t / 7) * 56 + (t % 7)] = obuf[t * 196 + oc] + bo[oc];
    }
  }
}

extern "C" void kernel_launch(void* const* d_in, const int* in_sizes, int n_in,
                              void* d_out, int out_size, void* d_ws, size_t ws_size,
                              hipStream_t stream)
{
  const float* x    = (const float*)d_in[0];
  const float* mask = (const float*)d_in[1];
  const float* Wq   = (const float*)d_in[2];
  const float* Wkv  = (const float*)d_in[3];
  const float* Wo   = (const float*)d_in[4];
  const float* bo   = (const float*)d_in[5];
  const float* pos  = (const float*)d_in[6];

  float* out  = (float*)d_out;
  float* attn = out + OUT0;

  char* ws = (char*)d_ws;
  unsigned short* xt   = (unsigned short*)ws;
  unsigned short* qws  = (unsigned short*)(ws + Q_OFF);
  unsigned short* kws  = (unsigned short*)(ws + K_OFF);
  unsigned short* vt   = (unsigned short*)(ws + V_OFF);
  unsigned short* wqkv = (unsigned short*)(ws + WQKV_OFF);
  unsigned short* wo   = (unsigned short*)(ws + WO_OFF);
  float*          bias = (float*)(ws + BIAS_OFF);

  xt_prep<<<NWIN, 256, 0, stream>>>(x, mask, Wq, Wkv, Wo, pos, xt, wqkv, wo, bias);
  qkvv_gemm<<<6144, 256, 0, stream>>>(xt, wqkv, qws, kws, vt);
  la_attn<<<NWIN, 512, 0, stream>>>(qws, kws, vt, wo, bias, bo, attn, out);
}

// Round 6
// 408.128 us; speedup vs baseline: 14.2720x; 1.0065x over previous
//
#include <hip/hip_runtime.h>

// LocalAttention P=7 window attention — split-pipeline bf16 MFMA.
// Round 6: split la_attn (latency-bound, 2 blk/CU, barrier-coupled) into
//   attn_core: 1 wave = 1 (win,head), NO barriers, 25KB LDS -> ~6 blk/CU
//   out_proj : per-window Wo GEMM, obuf-only LDS (38.4KB) -> 4 blk/CU
// O[win][h][49][32] bf16 aliases the dead xt region (xt padded 64->68 rows
// so O fits; kernels are stream-ordered so the alias is race-free).

#define NWIN 2048
#define OUT0 19267584L
#define XT_T 68   // padded t-rows per window (only 0..63 written/read as xt)

typedef __attribute__((ext_vector_type(8))) short bf16x8;
typedef __attribute__((ext_vector_type(4))) float f32x4;

#define MFMA(a, b, c) __builtin_amdgcn_mfma_f32_16x16x32_bf16(a, b, c, 0, 0, 0)

__device__ __forceinline__ unsigned short f2b(float f) {
  unsigned u = __builtin_bit_cast(unsigned, f);
  return (unsigned short)((u + 0x7FFFu + ((u >> 16) & 1u)) >> 16);
}
__device__ __forceinline__ unsigned pk2(float a, float b) {
  return (unsigned)f2b(a) | ((unsigned)f2b(b) << 16);
}
__device__ __forceinline__ float b2f(unsigned short h) {
  unsigned u = ((unsigned)h) << 16;
  return __builtin_bit_cast(float, u);
}

// ---- workspace layout ----
#define XT_BYTES   (2048L * XT_T * 192 * 2)   // 53,477,376 (O needs 51,380,224)
#define QK_ROWS    (2048L * 49 + 64)
#define Q_OFF      XT_BYTES
#define K_OFF      (Q_OFF + QK_ROWS * 256 * 2)
#define V_OFF      (K_OFF + QK_ROWS * 256 * 2)
#define WQKV_OFF   (V_OFF + 2048L * 256 * 64 * 2)
#define WO_OFF     (WQKV_OFF + 768L * 192 * 2)
#define BIAS_OFF   (WO_OFF + 192L * 256 * 2)

// ================= K1: window transpose + prep =================
__global__ __launch_bounds__(256) void xt_prep(
    const float* __restrict__ x, const float* __restrict__ mask,
    const float* __restrict__ Wq, const float* __restrict__ Wkv,
    const float* __restrict__ Wo, const float* __restrict__ pos,
    unsigned short* __restrict__ xt, unsigned short* __restrict__ wqkv,
    unsigned short* __restrict__ wo, float* __restrict__ bias)
{
  __shared__ float sXw[192][53];
  const int tid = threadIdx.x;
  const int widx = blockIdx.x;
  const int bi = widx >> 6, w1 = (widx >> 3) & 7, w2 = widx & 7;
  const long xbase = (long)bi * 192 * 3136 + (w1 * 7) * 56 + w2 * 7;

  for (int idx = tid; idx < 192 * 49; idx += 256) {
    int c = idx / 49, t = idx - c * 49;
    sXw[c][t] = x[xbase + c * 3136 + (t / 7) * 56 + (t % 7)];
  }
  {
    int gid = widx * 256 + tid;
    if (gid < 147456)       wqkv[gid] = f2b(gid < 49152 ? Wq[gid] : Wkv[gid - 49152]);
    else if (gid < 196608)  { int i = gid - 147456; wo[i] = f2b(Wo[i]); }
    else if (gid < 199009)  {
      int i = gid - 196608;
      int tq = i / 49, tk = i - tq * 49;
      int r0 = tk / 7 - tq / 7 + 6, r1 = tk % 7 - tq % 7 + 6;
      bias[i] = mask[i] + pos[r0 * 13 + r1];
    }
  }
  __syncthreads();
  unsigned short* xw = xt + (long)widx * (XT_T * 192);
  for (int idx = tid; idx < 64 * 192; idx += 256) {
    int t = idx / 192, c = idx - t * 192;
    xw[t * 192 + c] = (t < 49) ? f2b(sXw[c][t]) : (unsigned short)0;
  }
}

// ================= K2: QKV GEMMs (no LDS, direct frags) =================
__global__ __launch_bounds__(256, 3) void qkvv_gemm(
    const unsigned short* __restrict__ xt, const unsigned short* __restrict__ wqkv,
    unsigned short* __restrict__ qws, unsigned short* __restrict__ kws,
    unsigned short* __restrict__ vt)
{
  const int tid = threadIdx.x;
  const int w = tid >> 6, lane = tid & 63;
  const int l15 = lane & 15, lg = lane >> 4;
  const int wr = w >> 1, wc = w & 1;
  const int bid = blockIdx.x;
  const f32x4 zero = {0.f, 0.f, 0.f, 0.f};
  f32x4 acc[4][4];
  #pragma unroll
  for (int i = 0; i < 4; ++i)
    #pragma unroll
    for (int j = 0; j < 4; ++j) acc[i][j] = zero;

  if (bid < 4096) {
    const int mt = bid & 3;
    const long n0 = (long)(bid >> 2) * 128 + wc * 64;   // multiple of 64
    const int winb = (int)(n0 >> 6);
    const int e_base = mt * 128 + wr * 64;
    #pragma unroll
    for (int ks = 0; ks < 6; ++ks) {
      const int kc = ks * 32 + lg * 8;
      bf16x8 a[4], b[4];
      #pragma unroll
      for (int mi = 0; mi < 4; ++mi)
        a[mi] = *(const bf16x8*)(wqkv + (e_base + mi * 16 + l15) * 192 + kc);
      #pragma unroll
      for (int ni = 0; ni < 4; ++ni)
        b[ni] = *(const bf16x8*)(xt + ((long)winb * XT_T + ni * 16 + l15) * 192 + kc);
      #pragma unroll
      for (int mi = 0; mi < 4; ++mi)
        #pragma unroll
        for (int ni = 0; ni < 4; ++ni)
          acc[mi][ni] = MFMA(a[mi], b[ni], acc[mi][ni]);
    }
    #pragma unroll
    for (int ni = 0; ni < 4; ++ni) {
      int tq = ni * 16 + l15;
      if (tq < 49) {
        #pragma unroll
        for (int mi = 0; mi < 4; ++mi) {
          int e0 = e_base + mi * 16 + lg * 4;
          unsigned short* dst = (e0 < 256) ? qws : kws;
          int e = e0 & 255;
          uint2 v = {pk2(acc[mi][ni][0], acc[mi][ni][1]),
                     pk2(acc[mi][ni][2], acc[mi][ni][3])};
          *(uint2*)(dst + ((long)winb * 49 + tq) * 256 + e) = v;
        }
      }
    }
  } else {
    const int vb = bid - 4096;
    const long t0 = (long)(vb >> 1) * 128 + wr * 64;    // multiple of 64
    const int winv = (int)(t0 >> 6);
    const int e_n0 = (vb & 1) * 128 + wc * 64;
    #pragma unroll
    for (int ks = 0; ks < 6; ++ks) {
      const int kc = ks * 32 + lg * 8;
      bf16x8 a[4], b[4];
      #pragma unroll
      for (int mi = 0; mi < 4; ++mi)
        a[mi] = *(const bf16x8*)(xt + ((long)winv * XT_T + mi * 16 + l15) * 192 + kc);
      #pragma unroll
      for (int ni = 0; ni < 4; ++ni)
        b[ni] = *(const bf16x8*)(wqkv + (512 + e_n0 + ni * 16 + l15) * 192 + kc);
      #pragma unroll
      for (int mi = 0; mi < 4; ++mi)
        #pragma unroll
        for (int ni = 0; ni < 4; ++ni)
          acc[mi][ni] = MFMA(a[mi], b[ni], acc[mi][ni]);
    }
    #pragma unroll
    for (int mi = 0; mi < 4; ++mi) {
      int tl = mi * 16 + lg * 4;
      #pragma unroll
      for (int ni = 0; ni < 4; ++ni) {
        int e = e_n0 + ni * 16 + l15;
        uint2 v = {pk2(acc[mi][ni][0], acc[mi][ni][1]),
                   pk2(acc[mi][ni][2], acc[mi][ni][3])};
        *(uint2*)(vt + ((long)winv * 256 + e) * 64 + tl) = v;
      }
    }
  }
}

// ================= K3a: attention core (1 wave = 1 (win,head)) =================
// LDS: P per-wave [49][64] bf16 swz, 6272 B/wave x 4 waves = 25088 B. No barriers.
#define PSTRIDE 6272

__global__ __launch_bounds__(256, 4) void attn_core(
    const unsigned short* __restrict__ qws, const unsigned short* __restrict__ kws,
    const unsigned short* __restrict__ vt, const float* __restrict__ bias,
    float* __restrict__ attn_out, unsigned short* __restrict__ o_ws)
{
  __shared__ __align__(16) char lds[4 * PSTRIDE];
  const int tid = threadIdx.x;
  const int w = tid >> 6, lane = tid & 63;
  const int l15 = lane & 15, lg = lane >> 4;
  const int gw = blockIdx.x * 4 + w;     // global wave id = (win,h)
  const int win = gw >> 3, h = gw & 7;
  const f32x4 zero = {0.f, 0.f, 0.f, 0.f};

  // ---- S = K.Q^T ----
  f32x4 s[4][4];
  {
    const long qkb = (long)win * 49 * 256 + h * 32 + lg * 8;
    bf16x8 ak[4], bq[4];
    #pragma unroll
    for (int mi = 0; mi < 4; ++mi)
      ak[mi] = *(const bf16x8*)(kws + qkb + (mi * 16 + l15) * 256);
    #pragma unroll
    for (int ni = 0; ni < 4; ++ni)
      bq[ni] = *(const bf16x8*)(qws + qkb + (ni * 16 + l15) * 256);
    #pragma unroll
    for (int mi = 0; mi < 4; ++mi)
      #pragma unroll
      for (int ni = 0; ni < 4; ++ni)
        s[mi][ni] = MFMA(ak[mi], bq[ni], zero);
  }

  // ---- softmax over tk per tq-column ----
  const float scale = 0.17677669529663687f;
  #pragma unroll
  for (int ni = 0; ni < 4; ++ni) {
    int tq = ni * 16 + l15;
    int tqc = tq < 49 ? tq : 48;
    #pragma unroll
    for (int mi = 0; mi < 4; ++mi)
      #pragma unroll
      for (int r = 0; r < 4; ++r) {
        int tk = mi * 16 + lg * 4 + r;
        float v = s[mi][ni][r];
        s[mi][ni][r] = (tk < 49) ? (v * scale + bias[tqc * 49 + tk]) : -1e30f;
      }
    float m = -1e30f;
    #pragma unroll
    for (int mi = 0; mi < 4; ++mi)
      #pragma unroll
      for (int r = 0; r < 4; ++r) m = fmaxf(m, s[mi][ni][r]);
    m = fmaxf(m, __shfl_xor(m, 16));
    m = fmaxf(m, __shfl_xor(m, 32));
    float sum = 0.f;
    #pragma unroll
    for (int mi = 0; mi < 4; ++mi)
      #pragma unroll
      for (int r = 0; r < 4; ++r) {
        float e = __expf(s[mi][ni][r] - m);
        s[mi][ni][r] = e;
        sum += e;
      }
    sum += __shfl_xor(sum, 16);
    sum += __shfl_xor(sum, 32);
    float inv = 1.0f / sum;
    #pragma unroll
    for (int mi = 0; mi < 4; ++mi)
      #pragma unroll
      for (int r = 0; r < 4; ++r) s[mi][ni][r] *= inv;
  }

  // ---- P -> wave-private LDS (bf16, swizzled, 49 rows) ----
  char* pw = lds + w * PSTRIDE;
  #pragma unroll
  for (int ni = 0; ni < 4; ++ni) {
    int tq = ni * 16 + l15;
    if (tq < 49) {
      #pragma unroll
      for (int mi = 0; mi < 4; ++mi) {
        int tk0 = mi * 16 + lg * 4;
        uint2 v = {pk2(s[mi][ni][0], s[mi][ni][1]),
                   pk2(s[mi][ni][2], s[mi][ni][3])};
        *(uint2*)(pw + tq * 128 + ((tk0 * 2) ^ ((tq & 7) << 4))) = v;
      }
    }
  }

  // ---- attn out: coalesced stream of this head's P (overlaps PV below) ----
  {
    float* abase = attn_out + ((long)win * 8 + h) * 2401;
    #pragma unroll
    for (int it = 0; it < 38; ++it) {
      int f = it * 64 + lane;
      if (f < 2401) {
        int tq = f / 49, tk = f - tq * 49;
        unsigned short pv =
            *(const unsigned short*)(pw + tq * 128 + ((tk * 2) ^ ((tq & 7) << 4)));
        abase[f] = b2f(pv);
      }
    }
  }

  // ---- O = Vt.P^T -> o_ws[win][h][49][32] bf16 ----
  {
    f32x4 o[2][4];
    #pragma unroll
    for (int i = 0; i < 2; ++i)
      #pragma unroll
      for (int j = 0; j < 4; ++j) o[i][j] = zero;
    #pragma unroll
    for (int ks = 0; ks < 2; ++ks) {
      const int tkc = ks * 32 + lg * 8;
      bf16x8 av[2], bp[4];
      #pragma unroll
      for (int mi = 0; mi < 2; ++mi) {
        int e = h * 32 + mi * 16 + l15;
        av[mi] = *(const bf16x8*)(vt + ((long)win * 256 + e) * 64 + tkc);
      }
      #pragma unroll
      for (int ni = 0; ni < 4; ++ni) {
        int tq = ni * 16 + l15;
        int tqc = tq < 49 ? tq : 48;
        bp[ni] = *(const bf16x8*)(pw + tqc * 128 + ((tkc * 2) ^ ((tqc & 7) << 4)));
      }
      #pragma unroll
      for (int mi = 0; mi < 2; ++mi)
        #pragma unroll
        for (int ni = 0; ni < 4; ++ni)
          o[mi][ni] = MFMA(av[mi], bp[ni], o[mi][ni]);
    }
    unsigned short* ob = o_ws + ((long)win * 8 + h) * 49 * 32;
    #pragma unroll
    for (int mi = 0; mi < 2; ++mi)
      #pragma unroll
      for (int ni = 0; ni < 4; ++ni) {
        int tq = ni * 16 + l15;
        if (tq < 49) {
          int el0 = mi * 16 + lg * 4;
          uint2 v = {pk2(o[mi][ni][0], o[mi][ni][1]),
                     pk2(o[mi][ni][2], o[mi][ni][3])};
          *(uint2*)(ob + tq * 32 + el0) = v;
        }
      }
  }
}

// ================= K3b: output projection =================
// wave w: oc-tiles w*3..w*3+2, t-tiles 0..3. B-frags straight from o_ws.
__global__ __launch_bounds__(256, 4) void out_proj(
    const unsigned short* __restrict__ o_ws, const unsigned short* __restrict__ wo,
    const float* __restrict__ bo, float* __restrict__ out)
{
  __shared__ __align__(16) float obuf[49 * 196];
  const int tid = threadIdx.x;
  const int w = tid >> 6, lane = tid & 63;
  const int l15 = lane & 15, lg = lane >> 4;
  const int win = blockIdx.x;
  const int bi = win >> 6, w1 = (win >> 3) & 7, w2 = win & 7;
  const f32x4 zero = {0.f, 0.f, 0.f, 0.f};

  f32x4 acc[3][4];
  #pragma unroll
  for (int j = 0; j < 3; ++j)
    #pragma unroll
    for (int tt = 0; tt < 4; ++tt) acc[j][tt] = zero;

  const int tO = lg * 0 + l15;  // t within tile = l15
  #pragma unroll
  for (int ks = 0; ks < 8; ++ks) {         // K = 256, head ks holds e 32*ks..+32
    const int ec = ks * 32 + lg * 8;
    bf16x8 aW[3], bO[4];
    #pragma unroll
    for (int j = 0; j < 3; ++j)
      aW[j] = *(const bf16x8*)(wo + ((w * 3 + j) * 16 + l15) * 256 + ec);
    #pragma unroll
    for (int tt = 0; tt < 4; ++tt) {
      int t = tt * 16 + l15;
      int tc = t < 49 ? t : 48;
      bO[tt] = *(const bf16x8*)(o_ws + ((long)(win * 8 + ks) * 49 + tc) * 32 + lg * 8);
    }
    #pragma unroll
    for (int j = 0; j < 3; ++j)
      #pragma unroll
      for (int tt = 0; tt < 4; ++tt)
        acc[j][tt] = MFMA(aW[j], bO[tt], acc[j][tt]);
  }
  #pragma unroll
  for (int j = 0; j < 3; ++j)
    #pragma unroll
    for (int tt = 0; tt < 4; ++tt) {
      int t = tt * 16 + l15;
      if (t < 49) {
        int oc0 = (w * 3 + j) * 16 + lg * 4;
        *(f32x4*)(obuf + t * 196 + oc0) = acc[j][tt];
      }
    }
  __syncthreads();

  const long obase = (long)bi * 602112 + (w1 * 7) * 56 + w2 * 7;
  for (int idx = tid; idx < 192 * 49; idx += 256) {
    int oc = idx / 49, t = idx - oc * 49;
    out[obase + oc * 3136 + (t / 7) * 56 + (t % 7)] = obuf[t * 196 + oc] + bo[oc];
  }
}

extern "C" void kernel_launch(void* const* d_in, const int* in_sizes, int n_in,
                              void* d_out, int out_size, void* d_ws, size_t ws_size,
                              hipStream_t stream)
{
  const float* x    = (const float*)d_in[0];
  const float* mask = (const float*)d_in[1];
  const float* Wq   = (const float*)d_in[2];
  const float* Wkv  = (const float*)d_in[3];
  const float* Wo   = (const float*)d_in[4];
  const float* bo   = (const float*)d_in[5];
  const float* pos  = (const float*)d_in[6];

  float* out  = (float*)d_out;
  float* attn = out + OUT0;

  char* ws = (char*)d_ws;
  unsigned short* xt   = (unsigned short*)ws;
  unsigned short* o_ws = (unsigned short*)ws;   // aliases xt (dead after K2)
  unsigned short* qws  = (unsigned short*)(ws + Q_OFF);
  unsigned short* kws  = (unsigned short*)(ws + K_OFF);
  unsigned short* vt   = (unsigned short*)(ws + V_OFF);
  unsigned short* wqkv = (unsigned short*)(ws + WQKV_OFF);
  unsigned short* wo   = (unsigned short*)(ws + WO_OFF);
  float*          bias = (float*)(ws + BIAS_OFF);

  xt_prep<<<NWIN, 256, 0, stream>>>(x, mask, Wq, Wkv, Wo, pos, xt, wqkv, wo, bias);
  qkvv_gemm<<<6144, 256, 0, stream>>>(xt, wqkv, qws, kws, vt);
  attn_core<<<4096, 256, 0, stream>>>(qws, kws, vt, bias, attn, o_ws);
  out_proj<<<NWIN, 256, 0, stream>>>(o_ws, wo, bo, out);
}

// Round 7
// 372.523 us; speedup vs baseline: 15.6361x; 1.0956x over previous
//
#include <hip/hip_runtime.h>

// LocalAttention P=7 window attention — split-pipeline bf16 MFMA.
// Round 7: qkvv_gemm was latency-bound (167us for ~5us of MFMA + ~50us of
// traffic; every B-frag a 16-line global load, zero reuse). Rewritten as an
// LDS-staged per-window GEMM: stage xt window (24KB) once, 4 waves x 3 tiles
// (Q,K,V) read B-frags from LDS (row pad 200 -> 2-way bank alias = free).
// K1/K3a/K3b unchanged from round 6 for clean A/B.

#define NWIN 2048
#define OUT0 19267584L
#define XT_T 68   // padded t-rows per window (o_ws alias space)

typedef __attribute__((ext_vector_type(8))) short bf16x8;
typedef __attribute__((ext_vector_type(4))) float f32x4;

#define MFMA(a, b, c) __builtin_amdgcn_mfma_f32_16x16x32_bf16(a, b, c, 0, 0, 0)

__device__ __forceinline__ unsigned short f2b(float f) {
  unsigned u = __builtin_bit_cast(unsigned, f);
  return (unsigned short)((u + 0x7FFFu + ((u >> 16) & 1u)) >> 16);
}
__device__ __forceinline__ unsigned pk2(float a, float b) {
  return (unsigned)f2b(a) | ((unsigned)f2b(b) << 16);
}
__device__ __forceinline__ float b2f(unsigned short h) {
  unsigned u = ((unsigned)h) << 16;
  return __builtin_bit_cast(float, u);
}

// ---- workspace layout ----
#define XT_BYTES   (2048L * XT_T * 192 * 2)
#define QK_ROWS    (2048L * 49 + 64)
#define Q_OFF      XT_BYTES
#define K_OFF      (Q_OFF + QK_ROWS * 256 * 2)
#define V_OFF      (K_OFF + QK_ROWS * 256 * 2)
#define WQKV_OFF   (V_OFF + 2048L * 256 * 64 * 2)
#define WO_OFF     (WQKV_OFF + 768L * 192 * 2)
#define BIAS_OFF   (WO_OFF + 192L * 256 * 2)

// ================= K1: window transpose + prep =================
__global__ __launch_bounds__(256) void xt_prep(
    const float* __restrict__ x, const float* __restrict__ mask,
    const float* __restrict__ Wq, const float* __restrict__ Wkv,
    const float* __restrict__ Wo, const float* __restrict__ pos,
    unsigned short* __restrict__ xt, unsigned short* __restrict__ wqkv,
    unsigned short* __restrict__ wo, float* __restrict__ bias)
{
  __shared__ float sXw[192][53];
  const int tid = threadIdx.x;
  const int widx = blockIdx.x;
  const int bi = widx >> 6, w1 = (widx >> 3) & 7, w2 = widx & 7;
  const long xbase = (long)bi * 192 * 3136 + (w1 * 7) * 56 + w2 * 7;

  for (int idx = tid; idx < 192 * 49; idx += 256) {
    int c = idx / 49, t = idx - c * 49;
    sXw[c][t] = x[xbase + c * 3136 + (t / 7) * 56 + (t % 7)];
  }
  {
    int gid = widx * 256 + tid;
    if (gid < 147456)       wqkv[gid] = f2b(gid < 49152 ? Wq[gid] : Wkv[gid - 49152]);
    else if (gid < 196608)  { int i = gid - 147456; wo[i] = f2b(Wo[i]); }
    else if (gid < 199009)  {
      int i = gid - 196608;
      int tq = i / 49, tk = i - tq * 49;
      int r0 = tk / 7 - tq / 7 + 6, r1 = tk % 7 - tq % 7 + 6;
      bias[i] = mask[i] + pos[r0 * 13 + r1];
    }
  }
  __syncthreads();
  unsigned short* xw = xt + (long)widx * (XT_T * 192);
  for (int idx = tid; idx < 64 * 192; idx += 256) {
    int t = idx / 192, c = idx - t * 192;
    xw[t * 192 + c] = (t < 49) ? f2b(sXw[c][t]) : (unsigned short)0;
  }
}

// ================= K2: per-window QKV GEMM, LDS-staged =================
// Block = 1 window, 4 waves. LDS xw [64][200] bf16 (pad 200: dword stride
// 100 = 4 mod 32 -> 2-way bank alias, free). Wave w does tiles ti=i*4+w,
// i=0..2: ti 0..7 -> Q/K rows (A=weights,B=xw), ti 8..11 -> V (A=xw,
// B=weights, so the packed store runs along t).
__global__ __launch_bounds__(256, 4) void qkvv_gemm(
    const unsigned short* __restrict__ xt, const unsigned short* __restrict__ wqkv,
    unsigned short* __restrict__ qws, unsigned short* __restrict__ kws,
    unsigned short* __restrict__ vt)
{
  __shared__ __align__(16) unsigned short xw[64 * 200];  // 25600 B
  const int tid = threadIdx.x;
  const int w = tid >> 6, lane = tid & 63;
  const int l15 = lane & 15, lg = lane >> 4;
  const int win = blockIdx.x;
  const f32x4 zero = {0.f, 0.f, 0.f, 0.f};

  // ---- stage xt window -> LDS (reg-staged, padded rows) ----
  {
    const unsigned short* xg = xt + (long)win * (XT_T * 192);
    #pragma unroll
    for (int i = 0; i < 12; ++i) {
      int chunk = i * 256 + tid;          // 3072 chunks of 8 u16
      int t = chunk / 24, c = (chunk - t * 24) * 8;
      bf16x8 v = *(const bf16x8*)(xg + t * 192 + c);
      *(bf16x8*)(xw + t * 200 + c) = v;
    }
  }
  __syncthreads();

  #pragma unroll
  for (int i = 0; i < 3; ++i) {
    const int ti = i * 4 + w;
    const int e_base = ti * 64;
    f32x4 acc[4][4];
    #pragma unroll
    for (int a = 0; a < 4; ++a)
      #pragma unroll
      for (int b = 0; b < 4; ++b) acc[a][b] = zero;

    if (i < 2) {
      // Q/K tile: D[e][t]
      #pragma unroll
      for (int ks = 0; ks < 6; ++ks) {
        const int kc = ks * 32 + lg * 8;
        bf16x8 a[4], b[4];
        #pragma unroll
        for (int mi = 0; mi < 4; ++mi)
          a[mi] = *(const bf16x8*)(wqkv + (e_base + mi * 16 + l15) * 192 + kc);
        #pragma unroll
        for (int ni = 0; ni < 4; ++ni)
          b[ni] = *(const bf16x8*)(xw + (ni * 16 + l15) * 200 + kc);
        #pragma unroll
        for (int mi = 0; mi < 4; ++mi)
          #pragma unroll
          for (int ni = 0; ni < 4; ++ni)
            acc[mi][ni] = MFMA(a[mi], b[ni], acc[mi][ni]);
      }
      #pragma unroll
      for (int ni = 0; ni < 4; ++ni) {
        int tq = ni * 16 + l15;
        if (tq < 49) {
          #pragma unroll
          for (int mi = 0; mi < 4; ++mi) {
            int e0 = e_base + mi * 16 + lg * 4;
            unsigned short* dst = (e0 < 256) ? qws : kws;
            int e = e0 & 255;
            uint2 v = {pk2(acc[mi][ni][0], acc[mi][ni][1]),
                       pk2(acc[mi][ni][2], acc[mi][ni][3])};
            *(uint2*)(dst + ((long)win * 49 + tq) * 256 + e) = v;
          }
        }
      }
    } else {
      // V tile: D[t][e], e_v = e_base-512 + ...
      const int ev0 = e_base - 512;
      #pragma unroll
      for (int ks = 0; ks < 6; ++ks) {
        const int kc = ks * 32 + lg * 8;
        bf16x8 a[4], b[4];
        #pragma unroll
        for (int mi = 0; mi < 4; ++mi)
          a[mi] = *(const bf16x8*)(xw + (mi * 16 + l15) * 200 + kc);
        #pragma unroll
        for (int ni = 0; ni < 4; ++ni)
          b[ni] = *(const bf16x8*)(wqkv + (512 + ev0 + ni * 16 + l15) * 192 + kc);
        #pragma unroll
        for (int mi = 0; mi < 4; ++mi)
          #pragma unroll
          for (int ni = 0; ni < 4; ++ni)
            acc[mi][ni] = MFMA(a[mi], b[ni], acc[mi][ni]);
      }
      #pragma unroll
      for (int mi = 0; mi < 4; ++mi) {
        int tl = mi * 16 + lg * 4;
        #pragma unroll
        for (int ni = 0; ni < 4; ++ni) {
          int e = ev0 + ni * 16 + l15;
          uint2 v = {pk2(acc[mi][ni][0], acc[mi][ni][1]),
                     pk2(acc[mi][ni][2], acc[mi][ni][3])};
          *(uint2*)(vt + ((long)win * 256 + e) * 64 + tl) = v;
        }
      }
    }
  }
}

// ================= K3a: attention core (1 wave = 1 (win,head)) =================
#define PSTRIDE 6272

__global__ __launch_bounds__(256, 4) void attn_core(
    const unsigned short* __restrict__ qws, const unsigned short* __restrict__ kws,
    const unsigned short* __restrict__ vt, const float* __restrict__ bias,
    float* __restrict__ attn_out, unsigned short* __restrict__ o_ws)
{
  __shared__ __align__(16) char lds[4 * PSTRIDE];
  const int tid = threadIdx.x;
  const int w = tid >> 6, lane = tid & 63;
  const int l15 = lane & 15, lg = lane >> 4;
  const int gw = blockIdx.x * 4 + w;
  const int win = gw >> 3, h = gw & 7;
  const f32x4 zero = {0.f, 0.f, 0.f, 0.f};

  // ---- S = K.Q^T ----
  f32x4 s[4][4];
  {
    const long qkb = (long)win * 49 * 256 + h * 32 + lg * 8;
    bf16x8 ak[4], bq[4];
    #pragma unroll
    for (int mi = 0; mi < 4; ++mi)
      ak[mi] = *(const bf16x8*)(kws + qkb + (mi * 16 + l15) * 256);
    #pragma unroll
    for (int ni = 0; ni < 4; ++ni)
      bq[ni] = *(const bf16x8*)(qws + qkb + (ni * 16 + l15) * 256);
    #pragma unroll
    for (int mi = 0; mi < 4; ++mi)
      #pragma unroll
      for (int ni = 0; ni < 4; ++ni)
        s[mi][ni] = MFMA(ak[mi], bq[ni], zero);
  }

  // ---- softmax over tk per tq-column ----
  const float scale = 0.17677669529663687f;
  #pragma unroll
  for (int ni = 0; ni < 4; ++ni) {
    int tq = ni * 16 + l15;
    int tqc = tq < 49 ? tq : 48;
    #pragma unroll
    for (int mi = 0; mi < 4; ++mi)
      #pragma unroll
      for (int r = 0; r < 4; ++r) {
        int tk = mi * 16 + lg * 4 + r;
        float v = s[mi][ni][r];
        s[mi][ni][r] = (tk < 49) ? (v * scale + bias[tqc * 49 + tk]) : -1e30f;
      }
    float m = -1e30f;
    #pragma unroll
    for (int mi = 0; mi < 4; ++mi)
      #pragma unroll
      for (int r = 0; r < 4; ++r) m = fmaxf(m, s[mi][ni][r]);
    m = fmaxf(m, __shfl_xor(m, 16));
    m = fmaxf(m, __shfl_xor(m, 32));
    float sum = 0.f;
    #pragma unroll
    for (int mi = 0; mi < 4; ++mi)
      #pragma unroll
      for (int r = 0; r < 4; ++r) {
        float e = __expf(s[mi][ni][r] - m);
        s[mi][ni][r] = e;
        sum += e;
      }
    sum += __shfl_xor(sum, 16);
    sum += __shfl_xor(sum, 32);
    float inv = 1.0f / sum;
    #pragma unroll
    for (int mi = 0; mi < 4; ++mi)
      #pragma unroll
      for (int r = 0; r < 4; ++r) s[mi][ni][r] *= inv;
  }

  // ---- P -> wave-private LDS (bf16, swizzled, 49 rows) ----
  char* pw = lds + w * PSTRIDE;
  #pragma unroll
  for (int ni = 0; ni < 4; ++ni) {
    int tq = ni * 16 + l15;
    if (tq < 49) {
      #pragma unroll
      for (int mi = 0; mi < 4; ++mi) {
        int tk0 = mi * 16 + lg * 4;
        uint2 v = {pk2(s[mi][ni][0], s[mi][ni][1]),
                   pk2(s[mi][ni][2], s[mi][ni][3])};
        *(uint2*)(pw + tq * 128 + ((tk0 * 2) ^ ((tq & 7) << 4))) = v;
      }
    }
  }

  // ---- attn out: coalesced stream (overlaps PV) ----
  {
    float* abase = attn_out + ((long)win * 8 + h) * 2401;
    #pragma unroll
    for (int it = 0; it < 38; ++it) {
      int f = it * 64 + lane;
      if (f < 2401) {
        int tq = f / 49, tk = f - tq * 49;
        unsigned short pv =
            *(const unsigned short*)(pw + tq * 128 + ((tk * 2) ^ ((tq & 7) << 4)));
        abase[f] = b2f(pv);
      }
    }
  }

  // ---- O = Vt.P^T -> o_ws[win][h][49][32] bf16 ----
  {
    f32x4 o[2][4];
    #pragma unroll
    for (int i = 0; i < 2; ++i)
      #pragma unroll
      for (int j = 0; j < 4; ++j) o[i][j] = zero;
    #pragma unroll
    for (int ks = 0; ks < 2; ++ks) {
      const int tkc = ks * 32 + lg * 8;
      bf16x8 av[2], bp[4];
      #pragma unroll
      for (int mi = 0; mi < 2; ++mi) {
        int e = h * 32 + mi * 16 + l15;
        av[mi] = *(const bf16x8*)(vt + ((long)win * 256 + e) * 64 + tkc);
      }
      #pragma unroll
      for (int ni = 0; ni < 4; ++ni) {
        int tq = ni * 16 + l15;
        int tqc = tq < 49 ? tq : 48;
        bp[ni] = *(const bf16x8*)(pw + tqc * 128 + ((tkc * 2) ^ ((tqc & 7) << 4)));
      }
      #pragma unroll
      for (int mi = 0; mi < 2; ++mi)
        #pragma unroll
        for (int ni = 0; ni < 4; ++ni)
          o[mi][ni] = MFMA(av[mi], bp[ni], o[mi][ni]);
    }
    unsigned short* ob = o_ws + ((long)win * 8 + h) * 49 * 32;
    #pragma unroll
    for (int mi = 0; mi < 2; ++mi)
      #pragma unroll
      for (int ni = 0; ni < 4; ++ni) {
        int tq = ni * 16 + l15;
        if (tq < 49) {
          int el0 = mi * 16 + lg * 4;
          uint2 v = {pk2(o[mi][ni][0], o[mi][ni][1]),
                     pk2(o[mi][ni][2], o[mi][ni][3])};
          *(uint2*)(ob + tq * 32 + el0) = v;
        }
      }
  }
}

// ================= K3b: output projection =================
__global__ __launch_bounds__(256, 4) void out_proj(
    const unsigned short* __restrict__ o_ws, const unsigned short* __restrict__ wo,
    const float* __restrict__ bo, float* __restrict__ out)
{
  __shared__ __align__(16) float obuf[49 * 196];
  const int tid = threadIdx.x;
  const int w = tid >> 6, lane = tid & 63;
  const int l15 = lane & 15, lg = lane >> 4;
  const int win = blockIdx.x;
  const int bi = win >> 6, w1 = (win >> 3) & 7, w2 = win & 7;
  const f32x4 zero = {0.f, 0.f, 0.f, 0.f};

  f32x4 acc[3][4];
  #pragma unroll
  for (int j = 0; j < 3; ++j)
    #pragma unroll
    for (int tt = 0; tt < 4; ++tt) acc[j][tt] = zero;

  #pragma unroll
  for (int ks = 0; ks < 8; ++ks) {
    const int ec = ks * 32 + lg * 8;
    bf16x8 aW[3], bO[4];
    #pragma unroll
    for (int j = 0; j < 3; ++j)
      aW[j] = *(const bf16x8*)(wo + ((w * 3 + j) * 16 + l15) * 256 + ec);
    #pragma unroll
    for (int tt = 0; tt < 4; ++tt) {
      int t = tt * 16 + l15;
      int tc = t < 49 ? t : 48;
      bO[tt] = *(const bf16x8*)(o_ws + ((long)(win * 8 + ks) * 49 + tc) * 32 + lg * 8);
    }
    #pragma unroll
    for (int j = 0; j < 3; ++j)
      #pragma unroll
      for (int tt = 0; tt < 4; ++tt)
        acc[j][tt] = MFMA(aW[j], bO[tt], acc[j][tt]);
  }
  #pragma unroll
  for (int j = 0; j < 3; ++j)
    #pragma unroll
    for (int tt = 0; tt < 4; ++tt) {
      int t = tt * 16 + l15;
      if (t < 49) {
        int oc0 = (w * 3 + j) * 16 + lg * 4;
        *(f32x4*)(obuf + t * 196 + oc0) = acc[j][tt];
      }
    }
  __syncthreads();

  const long obase = (long)bi * 602112 + (w1 * 7) * 56 + w2 * 7;
  for (int idx = tid; idx < 192 * 49; idx += 256) {
    int oc = idx / 49, t = idx - oc * 49;
    out[obase + oc * 3136 + (t / 7) * 56 + (t % 7)] = obuf[t * 196 + oc] + bo[oc];
  }
}

extern "C" void kernel_launch(void* const* d_in, const int* in_sizes, int n_in,
                              void* d_out, int out_size, void* d_ws, size_t ws_size,
                              hipStream_t stream)
{
  const float* x    = (const float*)d_in[0];
  const float* mask = (const float*)d_in[1];
  const float* Wq   = (const float*)d_in[2];
  const float* Wkv  = (const float*)d_in[3];
  const float* Wo   = (const float*)d_in[4];
  const float* bo   = (const float*)d_in[5];
  const float* pos  = (const float*)d_in[6];

  float* out  = (float*)d_out;
  float* attn = out + OUT0;

  char* ws = (char*)d_ws;
  unsigned short* xt   = (unsigned short*)ws;
  unsigned short* o_ws = (unsigned short*)ws;   // aliases xt (dead after K2)
  unsigned short* qws  = (unsigned short*)(ws + Q_OFF);
  unsigned short* kws  = (unsigned short*)(ws + K_OFF);
  unsigned short* vt   = (unsigned short*)(ws + V_OFF);
  unsigned short* wqkv = (unsigned short*)(ws + WQKV_OFF);
  unsigned short* wo   = (unsigned short*)(ws + WO_OFF);
  float*          bias = (float*)(ws + BIAS_OFF);

  xt_prep<<<NWIN, 256, 0, stream>>>(x, mask, Wq, Wkv, Wo, pos, xt, wqkv, wo, bias);
  qkvv_gemm<<<NWIN, 256, 0, stream>>>(xt, wqkv, qws, kws, vt);
  attn_core<<<4096, 256, 0, stream>>>(qws, kws, vt, bias, attn, o_ws);
  out_proj<<<NWIN, 256, 0, stream>>>(o_ws, wo, bo, out);
}

// Round 8
// 354.115 us; speedup vs baseline: 16.4489x; 1.0520x over previous
//
#include <hip/hip_runtime.h>

// LocalAttention P=7 window attention — split-pipeline bf16 MFMA.
// Round 8: fuse the window gather (xt_prep) into qkvv_gemm. The xt buffer was
// a pure roundtrip (write 50MB + read 50MB + an extra 77MB pass over x).
// qkvv now gathers x f32 -> bf16 straight into its LDS tile. Weight/bias cvt
// moves to a tiny prep kernel. attn_core / out_proj unchanged (clean A/B).

#define NWIN 2048
#define OUT0 19267584L

typedef __attribute__((ext_vector_type(8))) short bf16x8;
typedef __attribute__((ext_vector_type(4))) float f32x4;

#define MFMA(a, b, c) __builtin_amdgcn_mfma_f32_16x16x32_bf16(a, b, c, 0, 0, 0)

__device__ __forceinline__ unsigned short f2b(float f) {
  unsigned u = __builtin_bit_cast(unsigned, f);
  return (unsigned short)((u + 0x7FFFu + ((u >> 16) & 1u)) >> 16);
}
__device__ __forceinline__ unsigned pk2(float a, float b) {
  return (unsigned)f2b(a) | ((unsigned)f2b(b) << 16);
}
__device__ __forceinline__ float b2f(unsigned short h) {
  unsigned u = ((unsigned)h) << 16;
  return __builtin_bit_cast(float, u);
}

// ---- workspace layout (o_ws gets its own region; xt is gone) ----
#define OWS_BYTES  (2048L * 8 * 49 * 32 * 2)   // 51,380,224
#define QK_ROWS    (2048L * 49 + 64)
#define Q_OFF      OWS_BYTES
#define K_OFF      (Q_OFF + QK_ROWS * 256 * 2)
#define V_OFF      (K_OFF + QK_ROWS * 256 * 2)
#define WQKV_OFF   (V_OFF + 2048L * 256 * 64 * 2)
#define WO_OFF     (WQKV_OFF + 768L * 192 * 2)
#define BIAS_OFF   (WO_OFF + 192L * 256 * 2)

// ================= K0: weight cvt + bias table (tiny) =================
__global__ __launch_bounds__(256) void prep(
    const float* __restrict__ mask, const float* __restrict__ Wq,
    const float* __restrict__ Wkv, const float* __restrict__ Wo,
    const float* __restrict__ pos,
    unsigned short* __restrict__ wqkv, unsigned short* __restrict__ wo,
    float* __restrict__ bias)
{
  int gid = blockIdx.x * 256 + threadIdx.x;
  if (gid < 147456)       wqkv[gid] = f2b(gid < 49152 ? Wq[gid] : Wkv[gid - 49152]);
  else if (gid < 196608)  { int i = gid - 147456; wo[i] = f2b(Wo[i]); }
  else if (gid < 199009)  {
    int i = gid - 196608;
    int tq = i / 49, tk = i - tq * 49;
    int r0 = tk / 7 - tq / 7 + 6, r1 = tk % 7 - tq % 7 + 6;
    bias[i] = mask[i] + pos[r0 * 13 + r1];
  }
}

// ================= K1: per-window QKV GEMM, gathers x directly =================
// Block = 1 window, 4 waves. LDS xw [64][200] bf16. Gather x (f32, 28B runs,
// coalesced like old xt_prep) -> bf16 -> LDS transposed. Then wave w does
// tiles ti=i*4+w: ti 0..7 Q/K rows (A=weights,B=xw), ti 8..11 V (A=xw).
__global__ __launch_bounds__(256, 4) void qkvv_gemm(
    const float* __restrict__ x, const unsigned short* __restrict__ wqkv,
    unsigned short* __restrict__ qws, unsigned short* __restrict__ kws,
    unsigned short* __restrict__ vt)
{
  __shared__ __align__(16) unsigned short xw[64 * 200];  // 25600 B
  const int tid = threadIdx.x;
  const int w = tid >> 6, lane = tid & 63;
  const int l15 = lane & 15, lg = lane >> 4;
  const int win = blockIdx.x;
  const int bi = win >> 6, w1 = (win >> 3) & 7, w2 = win & 7;
  const f32x4 zero = {0.f, 0.f, 0.f, 0.f};

  // ---- gather x window -> LDS (transposed, bf16, zero-padded rows) ----
  {
    const long xbase = (long)bi * 192 * 3136 + (w1 * 7) * 56 + w2 * 7;
    for (int idx = tid; idx < 192 * 49; idx += 256) {
      int c = idx / 49, t = idx - c * 49;
      xw[t * 200 + c] = f2b(x[xbase + c * 3136 + (t / 7) * 56 + (t % 7)]);
    }
    for (int i = tid; i < 15 * 192; i += 256) {
      int t = 49 + i / 192, c = i - (i / 192) * 192;
      xw[t * 200 + c] = 0;
    }
  }
  __syncthreads();

  #pragma unroll
  for (int i = 0; i < 3; ++i) {
    const int ti = i * 4 + w;
    const int e_base = ti * 64;
    f32x4 acc[4][4];
    #pragma unroll
    for (int a = 0; a < 4; ++a)
      #pragma unroll
      for (int b = 0; b < 4; ++b) acc[a][b] = zero;

    if (i < 2) {
      // Q/K tile: D[e][t]
      #pragma unroll
      for (int ks = 0; ks < 6; ++ks) {
        const int kc = ks * 32 + lg * 8;
        bf16x8 a[4], b[4];
        #pragma unroll
        for (int mi = 0; mi < 4; ++mi)
          a[mi] = *(const bf16x8*)(wqkv + (e_base + mi * 16 + l15) * 192 + kc);
        #pragma unroll
        for (int ni = 0; ni < 4; ++ni)
          b[ni] = *(const bf16x8*)(xw + (ni * 16 + l15) * 200 + kc);
        #pragma unroll
        for (int mi = 0; mi < 4; ++mi)
          #pragma unroll
          for (int ni = 0; ni < 4; ++ni)
            acc[mi][ni] = MFMA(a[mi], b[ni], acc[mi][ni]);
      }
      #pragma unroll
      for (int ni = 0; ni < 4; ++ni) {
        int tq = ni * 16 + l15;
        if (tq < 49) {
          #pragma unroll
          for (int mi = 0; mi < 4; ++mi) {
            int e0 = e_base + mi * 16 + lg * 4;
            unsigned short* dst = (e0 < 256) ? qws : kws;
            int e = e0 & 255;
            uint2 v = {pk2(acc[mi][ni][0], acc[mi][ni][1]),
                       pk2(acc[mi][ni][2], acc[mi][ni][3])};
            *(uint2*)(dst + ((long)win * 49 + tq) * 256 + e) = v;
          }
        }
      }
    } else {
      // V tile: D[t][e]
      const int ev0 = e_base - 512;
      #pragma unroll
      for (int ks = 0; ks < 6; ++ks) {
        const int kc = ks * 32 + lg * 8;
        bf16x8 a[4], b[4];
        #pragma unroll
        for (int mi = 0; mi < 4; ++mi)
          a[mi] = *(const bf16x8*)(xw + (mi * 16 + l15) * 200 + kc);
        #pragma unroll
        for (int ni = 0; ni < 4; ++ni)
          b[ni] = *(const bf16x8*)(wqkv + (512 + ev0 + ni * 16 + l15) * 192 + kc);
        #pragma unroll
        for (int mi = 0; mi < 4; ++mi)
          #pragma unroll
          for (int ni = 0; ni < 4; ++ni)
            acc[mi][ni] = MFMA(a[mi], b[ni], acc[mi][ni]);
      }
      #pragma unroll
      for (int mi = 0; mi < 4; ++mi) {
        int tl = mi * 16 + lg * 4;
        #pragma unroll
        for (int ni = 0; ni < 4; ++ni) {
          int e = ev0 + ni * 16 + l15;
          uint2 v = {pk2(acc[mi][ni][0], acc[mi][ni][1]),
                     pk2(acc[mi][ni][2], acc[mi][ni][3])};
          *(uint2*)(vt + ((long)win * 256 + e) * 64 + tl) = v;
        }
      }
    }
  }
}

// ================= K2: attention core (1 wave = 1 (win,head)) =================
#define PSTRIDE 6272

__global__ __launch_bounds__(256, 4) void attn_core(
    const unsigned short* __restrict__ qws, const unsigned short* __restrict__ kws,
    const unsigned short* __restrict__ vt, const float* __restrict__ bias,
    float* __restrict__ attn_out, unsigned short* __restrict__ o_ws)
{
  __shared__ __align__(16) char lds[4 * PSTRIDE];
  const int tid = threadIdx.x;
  const int w = tid >> 6, lane = tid & 63;
  const int l15 = lane & 15, lg = lane >> 4;
  const int gw = blockIdx.x * 4 + w;
  const int win = gw >> 3, h = gw & 7;
  const f32x4 zero = {0.f, 0.f, 0.f, 0.f};

  // ---- S = K.Q^T ----
  f32x4 s[4][4];
  {
    const long qkb = (long)win * 49 * 256 + h * 32 + lg * 8;
    bf16x8 ak[4], bq[4];
    #pragma unroll
    for (int mi = 0; mi < 4; ++mi)
      ak[mi] = *(const bf16x8*)(kws + qkb + (mi * 16 + l15) * 256);
    #pragma unroll
    for (int ni = 0; ni < 4; ++ni)
      bq[ni] = *(const bf16x8*)(qws + qkb + (ni * 16 + l15) * 256);
    #pragma unroll
    for (int mi = 0; mi < 4; ++mi)
      #pragma unroll
      for (int ni = 0; ni < 4; ++ni)
        s[mi][ni] = MFMA(ak[mi], bq[ni], zero);
  }

  // ---- softmax over tk per tq-column ----
  const float scale = 0.17677669529663687f;
  #pragma unroll
  for (int ni = 0; ni < 4; ++ni) {
    int tq = ni * 16 + l15;
    int tqc = tq < 49 ? tq : 48;
    #pragma unroll
    for (int mi = 0; mi < 4; ++mi)
      #pragma unroll
      for (int r = 0; r < 4; ++r) {
        int tk = mi * 16 + lg * 4 + r;
        float v = s[mi][ni][r];
        s[mi][ni][r] = (tk < 49) ? (v * scale + bias[tqc * 49 + tk]) : -1e30f;
      }
    float m = -1e30f;
    #pragma unroll
    for (int mi = 0; mi < 4; ++mi)
      #pragma unroll
      for (int r = 0; r < 4; ++r) m = fmaxf(m, s[mi][ni][r]);
    m = fmaxf(m, __shfl_xor(m, 16));
    m = fmaxf(m, __shfl_xor(m, 32));
    float sum = 0.f;
    #pragma unroll
    for (int mi = 0; mi < 4; ++mi)
      #pragma unroll
      for (int r = 0; r < 4; ++r) {
        float e = __expf(s[mi][ni][r] - m);
        s[mi][ni][r] = e;
        sum += e;
      }
    sum += __shfl_xor(sum, 16);
    sum += __shfl_xor(sum, 32);
    float inv = 1.0f / sum;
    #pragma unroll
    for (int mi = 0; mi < 4; ++mi)
      #pragma unroll
      for (int r = 0; r < 4; ++r) s[mi][ni][r] *= inv;
  }

  // ---- P -> wave-private LDS (bf16, swizzled, 49 rows) ----
  char* pw = lds + w * PSTRIDE;
  #pragma unroll
  for (int ni = 0; ni < 4; ++ni) {
    int tq = ni * 16 + l15;
    if (tq < 49) {
      #pragma unroll
      for (int mi = 0; mi < 4; ++mi) {
        int tk0 = mi * 16 + lg * 4;
        uint2 v = {pk2(s[mi][ni][0], s[mi][ni][1]),
                   pk2(s[mi][ni][2], s[mi][ni][3])};
        *(uint2*)(pw + tq * 128 + ((tk0 * 2) ^ ((tq & 7) << 4))) = v;
      }
    }
  }

  // ---- attn out: coalesced stream (overlaps PV) ----
  {
    float* abase = attn_out + ((long)win * 8 + h) * 2401;
    #pragma unroll
    for (int it = 0; it < 38; ++it) {
      int f = it * 64 + lane;
      if (f < 2401) {
        int tq = f / 49, tk = f - tq * 49;
        unsigned short pv =
            *(const unsigned short*)(pw + tq * 128 + ((tk * 2) ^ ((tq & 7) << 4)));
        abase[f] = b2f(pv);
      }
    }
  }

  // ---- O = Vt.P^T -> o_ws[win][h][49][32] bf16 ----
  {
    f32x4 o[2][4];
    #pragma unroll
    for (int i = 0; i < 2; ++i)
      #pragma unroll
      for (int j = 0; j < 4; ++j) o[i][j] = zero;
    #pragma unroll
    for (int ks = 0; ks < 2; ++ks) {
      const int tkc = ks * 32 + lg * 8;
      bf16x8 av[2], bp[4];
      #pragma unroll
      for (int mi = 0; mi < 2; ++mi) {
        int e = h * 32 + mi * 16 + l15;
        av[mi] = *(const bf16x8*)(vt + ((long)win * 256 + e) * 64 + tkc);
      }
      #pragma unroll
      for (int ni = 0; ni < 4; ++ni) {
        int tq = ni * 16 + l15;
        int tqc = tq < 49 ? tq : 48;
        bp[ni] = *(const bf16x8*)(pw + tqc * 128 + ((tkc * 2) ^ ((tqc & 7) << 4)));
      }
      #pragma unroll
      for (int mi = 0; mi < 2; ++mi)
        #pragma unroll
        for (int ni = 0; ni < 4; ++ni)
          o[mi][ni] = MFMA(av[mi], bp[ni], o[mi][ni]);
    }
    unsigned short* ob = o_ws + ((long)win * 8 + h) * 49 * 32;
    #pragma unroll
    for (int mi = 0; mi < 2; ++mi)
      #pragma unroll
      for (int ni = 0; ni < 4; ++ni) {
        int tq = ni * 16 + l15;
        if (tq < 49) {
          int el0 = mi * 16 + lg * 4;
          uint2 v = {pk2(o[mi][ni][0], o[mi][ni][1]),
                     pk2(o[mi][ni][2], o[mi][ni][3])};
          *(uint2*)(ob + tq * 32 + el0) = v;
        }
      }
  }
}

// ================= K3: output projection =================
__global__ __launch_bounds__(256, 4) void out_proj(
    const unsigned short* __restrict__ o_ws, const unsigned short* __restrict__ wo,
    const float* __restrict__ bo, float* __restrict__ out)
{
  __shared__ __align__(16) float obuf[49 * 196];
  const int tid = threadIdx.x;
  const int w = tid >> 6, lane = tid & 63;
  const int l15 = lane & 15, lg = lane >> 4;
  const int win = blockIdx.x;
  const int bi = win >> 6, w1 = (win >> 3) & 7, w2 = win & 7;
  const f32x4 zero = {0.f, 0.f, 0.f, 0.f};

  f32x4 acc[3][4];
  #pragma unroll
  for (int j = 0; j < 3; ++j)
    #pragma unroll
    for (int tt = 0; tt < 4; ++tt) acc[j][tt] = zero;

  #pragma unroll
  for (int ks = 0; ks < 8; ++ks) {
    const int ec = ks * 32 + lg * 8;
    bf16x8 aW[3], bO[4];
    #pragma unroll
    for (int j = 0; j < 3; ++j)
      aW[j] = *(const bf16x8*)(wo + ((w * 3 + j) * 16 + l15) * 256 + ec);
    #pragma unroll
    for (int tt = 0; tt < 4; ++tt) {
      int t = tt * 16 + l15;
      int tc = t < 49 ? t : 48;
      bO[tt] = *(const bf16x8*)(o_ws + ((long)(win * 8 + ks) * 49 + tc) * 32 + lg * 8);
    }
    #pragma unroll
    for (int j = 0; j < 3; ++j)
      #pragma unroll
      for (int tt = 0; tt < 4; ++tt)
        acc[j][tt] = MFMA(aW[j], bO[tt], acc[j][tt]);
  }
  #pragma unroll
  for (int j = 0; j < 3; ++j)
    #pragma unroll
    for (int tt = 0; tt < 4; ++tt) {
      int t = tt * 16 + l15;
      if (t < 49) {
        int oc0 = (w * 3 + j) * 16 + lg * 4;
        *(f32x4*)(obuf + t * 196 + oc0) = acc[j][tt];
      }
    }
  __syncthreads();

  const long obase = (long)bi * 602112 + (w1 * 7) * 56 + w2 * 7;
  for (int idx = tid; idx < 192 * 49; idx += 256) {
    int oc = idx / 49, t = idx - oc * 49;
    out[obase + oc * 3136 + (t / 7) * 56 + (t % 7)] = obuf[t * 196 + oc] + bo[oc];
  }
}

extern "C" void kernel_launch(void* const* d_in, const int* in_sizes, int n_in,
                              void* d_out, int out_size, void* d_ws, size_t ws_size,
                              hipStream_t stream)
{
  const float* x    = (const float*)d_in[0];
  const float* mask = (const float*)d_in[1];
  const float* Wq   = (const float*)d_in[2];
  const float* Wkv  = (const float*)d_in[3];
  const float* Wo   = (const float*)d_in[4];
  const float* bo   = (const float*)d_in[5];
  const float* pos  = (const float*)d_in[6];

  float* out  = (float*)d_out;
  float* attn = out + OUT0;

  char* ws = (char*)d_ws;
  unsigned short* o_ws = (unsigned short*)ws;
  unsigned short* qws  = (unsigned short*)(ws + Q_OFF);
  unsigned short* kws  = (unsigned short*)(ws + K_OFF);
  unsigned short* vt   = (unsigned short*)(ws + V_OFF);
  unsigned short* wqkv = (unsigned short*)(ws + WQKV_OFF);
  unsigned short* wo   = (unsigned short*)(ws + WO_OFF);
  float*          bias = (float*)(ws + BIAS_OFF);

  prep<<<778, 256, 0, stream>>>(mask, Wq, Wkv, Wo, pos, wqkv, wo, bias);
  qkvv_gemm<<<NWIN, 256, 0, stream>>>(x, wqkv, qws, kws, vt);
  attn_core<<<4096, 256, 0, stream>>>(qws, kws, vt, bias, attn, o_ws);
  out_proj<<<NWIN, 256, 0, stream>>>(o_ws, wo, bo, out);
}